// Round 5
// baseline (3985.979 us; speedup 1.0000x reference)
//
#include <hip/hip_runtime.h>
#include <hip/hip_bf16.h>

using bf16 = __hip_bfloat16;

__device__ inline float b2f(bf16 h) { return __bfloat162float(h); }
__device__ inline bf16 f2b(float f) { return __float2bfloat16(f); }

__device__ inline float gelu_new(float x) {
    float x3 = x * x * x;
    return 0.5f * x * (1.0f + tanhf(0.7978845608028654f * (x + 0.044715f * x3)));
}

// ---------------- LayerNorm over [C,H,W] = 131072 per sample ----------------
// TIN = float (first LN reads f32 input x) or bf16 (second LN reads bf16 X1).
template <typename TIN>
__global__ __launch_bounds__(256) void ln_kernel(const TIN* __restrict__ x,
                                                 const float* __restrict__ g,
                                                 const float* __restrict__ bb,
                                                 bf16* __restrict__ out) {
    const int N = 131072;
    const int tid = threadIdx.x;
    const size_t base = (size_t)blockIdx.x * N;
    float sum = 0.f, ss = 0.f;
    for (int i = tid; i < N; i += 256) {
        float v;
        if constexpr (sizeof(TIN) == 2) v = b2f(((const bf16*)x)[base + i]);
        else                            v = ((const float*)x)[base + i];
        sum += v; ss += v * v;
    }
    __shared__ float rs[256], rs2[256];
    rs[tid] = sum; rs2[tid] = ss;
    __syncthreads();
    for (int off = 128; off > 0; off >>= 1) {
        if (tid < off) { rs[tid] += rs[tid + off]; rs2[tid] += rs2[tid + off]; }
        __syncthreads();
    }
    __shared__ float smean, srstd;
    if (tid == 0) {
        float m = rs[0] / (float)N;
        float var = rs2[0] / (float)N - m * m;
        smean = m;
        srstd = rsqrtf(var + 1e-5f);
    }
    __syncthreads();
    float m = smean, r = srstd;
    for (int i = tid; i < N; i += 256) {
        float v;
        if constexpr (sizeof(TIN) == 2) v = b2f(((const bf16*)x)[base + i]);
        else                            v = ((const float*)x)[base + i];
        out[base + i] = f2b((v - m) * r * g[i] + bb[i]);
    }
}

// ---------------- 3x3 conv, pad 1, input 64x64, templated ----------------
// EPI: 1 = plain
//      2 = +bias + residual   (residual f32 if RESF32 else bf16)
//      3 = +bias + GELU
// TOUT: bf16 or float output.
// in sample stride = CIN*4096 elems; out sample stride = cout_total*HO*WO.
// in_s0 / out_s0: sample offsets for chunked launches (res indexed like out).
template <int CIN, int COUT_PB, int STRIDE, int ROWS_PB, int EPI, bool RESF32, typename TOUT>
__global__ __launch_bounds__(256) void conv3x3_k(const bf16* __restrict__ in,
                                                 const float* __restrict__ wgt,
                                                 const float* __restrict__ bias,
                                                 const void* __restrict__ res,
                                                 TOUT* __restrict__ out,
                                                 int cout_total, int in_s0, int out_s0) {
    constexpr int WO = 64 / STRIDE;
    constexpr int HO = 64 / STRIDE;
    constexpr int NROWS = (STRIDE == 1) ? (ROWS_PB + 2) : (2 * ROWS_PB + 1);
    constexpr int LDSW = 66;
    constexpr int POS_PT = (ROWS_PB * WO) / 256;

    __shared__ float s_in[NROWS * LDSW];
    __shared__ float s_w[COUT_PB * CIN * 9];

    const int tid = threadIdx.x;
    const int CGRP = cout_total / COUT_PB;
    const int cg = blockIdx.x % CGRP;
    const int rt = blockIdx.x / CGRP;
    const int oc0 = cg * COUT_PB;
    const int r0 = rt * ROWS_PB;
    const int rowInStart = r0 * STRIDE - 1;

    for (int i = tid; i < COUT_PB * CIN * 9; i += 256) {
        int oc_l = i / (CIN * 9);
        int rem = i - oc_l * (CIN * 9);
        s_w[i] = wgt[(size_t)(oc0 + oc_l) * CIN * 9 + rem];
    }

    float acc[POS_PT][COUT_PB];
#pragma unroll
    for (int p = 0; p < POS_PT; ++p)
#pragma unroll
        for (int o = 0; o < COUT_PB; ++o) acc[p][o] = 0.f;

    const bf16* plane0 = in + (size_t)(in_s0 + blockIdx.y) * CIN * 4096;

    for (int ci = 0; ci < CIN; ++ci) {
        __syncthreads();  // first iter also covers s_w staging
        const bf16* plane = plane0 + (size_t)ci * 4096;
        for (int i = tid; i < NROWS * LDSW; i += 256) {
            int r = i / LDSW;
            int c = i - r * LDSW - 1;
            int iy = rowInStart + r;
            float v = 0.f;
            if (c >= 0 && c < 64 && iy >= 0 && iy < 64) v = b2f(plane[iy * 64 + c]);
            s_in[i] = v;
        }
        __syncthreads();
        float w[COUT_PB][9];
#pragma unroll
        for (int o = 0; o < COUT_PB; ++o)
#pragma unroll
            for (int j = 0; j < 9; ++j) w[o][j] = s_w[(o * CIN + ci) * 9 + j];
#pragma unroll
        for (int p = 0; p < POS_PT; ++p) {
            int pos = tid + p * 256;
            int oy_l = pos / WO;
            int ox = pos - oy_l * WO;
#pragma unroll
            for (int ky = 0; ky < 3; ++ky) {
                int rbase = (oy_l * STRIDE + ky) * LDSW + ox * STRIDE;
#pragma unroll
                for (int kx = 0; kx < 3; ++kx) {
                    float v = s_in[rbase + kx];
#pragma unroll
                    for (int o = 0; o < COUT_PB; ++o) acc[p][o] += v * w[o][ky * 3 + kx];
                }
            }
        }
    }

#pragma unroll
    for (int p = 0; p < POS_PT; ++p) {
        int pos = tid + p * 256;
        int oy_l = pos / WO;
        int ox = pos - oy_l * WO;
        int oy = r0 + oy_l;
#pragma unroll
        for (int o = 0; o < COUT_PB; ++o) {
            int oc = oc0 + o;
            size_t oidx = (((size_t)(out_s0 + blockIdx.y) * cout_total + oc) * HO + oy) * WO + ox;
            float v = acc[p][o];
            if constexpr (EPI == 2) {
                float rv;
                if constexpr (RESF32) rv = ((const float*)res)[oidx];
                else                  rv = b2f(((const bf16*)res)[oidx]);
                v += bias[oc] + rv;
            } else if constexpr (EPI == 3) {
                v = gelu_new(v + bias[oc]);
            }
            if constexpr (sizeof(TOUT) == 2) out[oidx] = f2b(v);
            else                             out[oidx] = v;
        }
    }
}

// ---------------- attention: scores + softmax (simple, correct) -------------
// One block per (b,h,t). LDS tree reduction, scalar bf16 reads.
// att layout [b][h][t][s] f32.
__global__ __launch_bounds__(256) void attn_fused_simple(const bf16* __restrict__ Q,
                                                         const bf16* __restrict__ K,
                                                         float* __restrict__ att) {
    __shared__ float s_q[4096];
    __shared__ float rs[256];
    __shared__ float s_att[32];
    const int tid = threadIdx.x;
    const int t = blockIdx.x & 31;
    const int h = (blockIdx.x >> 5) & 7;
    const int b = blockIdx.x >> 8;

    const bf16* qrow = Q + (size_t)(b * 32 + t) * 32768 + h * 4096;
    for (int i = tid; i < 4096; i += 256) s_q[i] = b2f(qrow[i]);
    __syncthreads();

    for (int s = 0; s < 32; ++s) {
        const bf16* krow = K + (size_t)(b * 32 + s) * 32768 + h * 4096;
        float p = 0.f;
        for (int d = tid; d < 4096; d += 256) p += s_q[d] * b2f(krow[d]);
        rs[tid] = p;
        __syncthreads();
        for (int off = 128; off > 0; off >>= 1) {
            if (tid < off) rs[tid] += rs[tid + off];
            __syncthreads();
        }
        if (tid == 0) s_att[s] = rs[0] * (1.0f / 64.0f);
        __syncthreads();
    }
    if (tid == 0) {
        float mx = -1e30f;
        for (int i = 0; i < 32; ++i) mx = fmaxf(mx, s_att[i]);
        float sum = 0.f;
        for (int i = 0; i < 32; ++i) { s_att[i] = expf(s_att[i] - mx); sum += s_att[i]; }
        float inv = 1.f / sum;
        for (int i = 0; i < 32; ++i) att[(size_t)blockIdx.x * 32 + i] = s_att[i] * inv;
    }
}

// ---------------- y = att @ v (simple, correct) ------------------------------
// One thread per output element (b,t,h,d). Scalar loads, coalesced in d.
__global__ __launch_bounds__(256) void attn_apply_simple(const float* __restrict__ att,
                                                         const bf16* __restrict__ V,
                                                         bf16* __restrict__ Y) {
    int gid = blockIdx.x * 256 + threadIdx.x;   // 2^24 threads total
    int d = gid & 16383;
    int h = (gid >> 14) & 7;
    int t = (gid >> 17) & 31;
    int b = gid >> 22;
    const float* arow = att + (size_t)(((b * 8 + h) * 32 + t) * 32);
    float acc = 0.f;
    for (int s = 0; s < 32; ++s)
        acc += arow[s] * b2f(V[(size_t)(b * 32 + s) * 131072 + h * 16384 + d]);
    Y[(size_t)(b * 32 + t) * 131072 + h * 16384 + d] = f2b(acc);
}

extern "C" void kernel_launch(void* const* d_in, const int* in_sizes, int n_in,
                              void* d_out, int out_size, void* d_ws, size_t ws_size,
                              hipStream_t stream) {
    // Inputs are float32; OUTPUT is float32 (reference returns jnp.float32).
    const float* x   = (const float*)d_in[0];
    const float* n1g = (const float*)d_in[1];
    const float* n1b = (const float*)d_in[2];
    const float* n2g = (const float*)d_in[3];
    const float* n2b = (const float*)d_in[4];
    const float* Wk  = (const float*)d_in[5];
    const float* Wq  = (const float*)d_in[6];
    const float* Wv  = (const float*)d_in[7];
    const float* Wo  = (const float*)d_in[8];
    const float* bo  = (const float*)d_in[9];
    const float* Wm1 = (const float*)d_in[10];
    const float* bm1 = (const float*)d_in[11];
    const float* Wm2 = (const float*)d_in[12];
    const float* bm2 = (const float*)d_in[13];

    char* ws = (char*)d_ws;
    // Region layout (bytes) — lifetimes disjoint on the stream:
    //  A [0, 33.5M):        xn -> Y -> xn2            (bf16, 128x32x64x64)
    //  B [33.5M, 67.1M):    V  -> X1                  (bf16, 128x32x64x64)
    //  D [67.1M, 67.24M):   att                       (f32, 4x8x32x32)
    //  C [67.24M, ws_end):  K(8.4M), Q(8.4M) -> Hb    (bf16)
    const size_t A_OFF  = 0;
    const size_t B_OFF  = 33554432;
    const size_t D_OFF  = 67108864;
    const size_t C_OFF  = 67239936;
    const size_t Q_OFF  = C_OFF + 8388608;

    bf16*  xn   = (bf16*)(ws + A_OFF);
    bf16*  Yb   = (bf16*)(ws + A_OFF);
    bf16*  xn2  = (bf16*)(ws + A_OFF);
    bf16*  Vb   = (bf16*)(ws + B_OFF);
    bf16*  X1   = (bf16*)(ws + B_OFF);
    float* attb = (float*)(ws + D_OFF);
    bf16*  Kb   = (bf16*)(ws + C_OFF);
    bf16*  Qb   = (bf16*)(ws + Q_OFF);
    bf16*  Hb   = (bf16*)(ws + C_OFF);   // overwrites K/Q (dead after attention)

    // Hb chunking: per-sample h is 128*4096 bf16 = 1 MiB.
    const size_t HB_PER_SAMPLE = 1048576;
    int chunk = 128;
    if (ws_size < C_OFF + 128 * HB_PER_SAMPLE) {
        size_t avail = (ws_size > C_OFF) ? (ws_size - C_OFF) : HB_PER_SAMPLE;
        chunk = (int)(avail / HB_PER_SAMPLE);
        if (chunk < 1) chunk = 1;
        if (chunk > 128) chunk = 128;
    }

    // 1. LN1: x (f32) -> xn (bf16)
    ln_kernel<float><<<128, 256, 0, stream>>>(x, n1g, n1b, xn);
    // 2-4. k,q (stride 2) -> bf16, v (stride 1) -> bf16
    conv3x3_k<32, 4, 2, 32, 1, false, bf16><<<dim3(8, 128), 256, 0, stream>>>(xn, Wk, nullptr, nullptr, Kb, 32, 0, 0);
    conv3x3_k<32, 4, 2, 32, 1, false, bf16><<<dim3(8, 128), 256, 0, stream>>>(xn, Wq, nullptr, nullptr, Qb, 32, 0, 0);
    conv3x3_k<32, 4, 1, 16, 1, false, bf16><<<dim3(32, 128), 256, 0, stream>>>(xn, Wv, nullptr, nullptr, Vb, 32, 0, 0);
    // 5. attention scores + softmax
    attn_fused_simple<<<1024, 256, 0, stream>>>(Qb, Kb, attb);
    // 6. y = att @ v  (Y overwrites xn — dead)
    attn_apply_simple<<<65536, 256, 0, stream>>>(attb, Vb, Yb);
    // 7. Wo conv + bias + residual x (f32) -> X1 bf16 (overwrites V — dead)
    conv3x3_k<32, 4, 1, 16, 2, true, bf16><<<dim3(32, 128), 256, 0, stream>>>(Yb, Wo, bo, x, X1, 32, 0, 0);
    // 8. LN2: X1 (bf16) -> xn2 (overwrites Y — dead)
    ln_kernel<bf16><<<128, 256, 0, stream>>>(X1, n2g, n2b, xn2);
    // 9-10. mixer, chunked over samples so Hb fits in ws; final write is f32.
    for (int s0 = 0; s0 < 128; s0 += chunk) {
        int n = (128 - s0 < chunk) ? (128 - s0) : chunk;
        conv3x3_k<32, 4, 1, 16, 3, false, bf16><<<dim3(128, n), 256, 0, stream>>>(xn2, Wm1, bm1, nullptr, Hb, 128, s0, 0);
        conv3x3_k<128, 4, 1, 16, 2, false, float><<<dim3(32, n), 256, 0, stream>>>(Hb, Wm2, bm2, X1, (float*)d_out, 32, 0, s0);
    }
}

// Round 6
// 1605.062 us; speedup vs baseline: 2.4834x; 2.4834x over previous
//
#include <hip/hip_runtime.h>
#include <hip/hip_bf16.h>

using bf16 = __hip_bfloat16;
typedef short bf16x8 __attribute__((ext_vector_type(8)));
typedef float f32x4 __attribute__((ext_vector_type(4)));

__device__ inline float b2f(bf16 h) { return __bfloat162float(h); }
__device__ inline bf16 f2b(float f) { return __float2bfloat16(f); }
__device__ inline unsigned short f2bu(float f) {
    bf16 h = __float2bfloat16(f);
    unsigned short u;
    __builtin_memcpy(&u, &h, 2);
    return u;
}
__device__ inline float su2f(unsigned short u) {  // bf16 bits -> float
    unsigned v = ((unsigned)u) << 16;
    return __uint_as_float(v);
}
__device__ inline float gelu_new(float x) {
    float x3 = x * x * x;
    return 0.5f * x * (1.0f + tanhf(0.7978845608028654f * (x + 0.044715f * x3)));
}

// ---------------- weight pack: [O][I][3][3] f32 -> [tap][O][I] bf16 ----------
__global__ __launch_bounds__(256) void pack_w(const float* __restrict__ w,
                                              bf16* __restrict__ wpk,
                                              int CO, int CI) {
    int i = blockIdx.x * 256 + threadIdx.x;
    int total = CO * CI * 9;
    if (i < total) {
        int tap = i % 9;
        int ci = (i / 9) % CI;
        int co = i / (9 * CI);
        wpk[((size_t)tap * CO + co) * CI + ci] = f2b(w[i]);
    }
}

// ---------------- LayerNorm over 131072 per sample ----------------
// MODE 0: in NCHW f32  -> out NHWC bf16  (first LN, reads input x)
// MODE 1: in NHWC bf16 -> out NHWC bf16  (second LN; g/b are NCHW-indexed)
template <int MODE>
__global__ __launch_bounds__(256) void ln_kernel(const void* __restrict__ xin,
                                                 const float* __restrict__ g,
                                                 const float* __restrict__ bb,
                                                 bf16* __restrict__ out) {
    const int N = 131072;
    const int tid = threadIdx.x;
    const size_t base = (size_t)blockIdx.x * N;
    float sum = 0.f, ss = 0.f;
    for (int i = tid; i < N; i += 256) {
        float v;
        if constexpr (MODE == 0) v = ((const float*)xin)[base + i];
        else                     v = b2f(((const bf16*)xin)[base + i]);
        sum += v; ss += v * v;
    }
    __shared__ float rs[256], rs2[256];
    rs[tid] = sum; rs2[tid] = ss;
    __syncthreads();
    for (int off = 128; off > 0; off >>= 1) {
        if (tid < off) { rs[tid] += rs[tid + off]; rs2[tid] += rs2[tid + off]; }
        __syncthreads();
    }
    __shared__ float smean, srstd;
    if (tid == 0) {
        float m = rs[0] / (float)N;
        float var = rs2[0] / (float)N - m * m;
        smean = m;
        srstd = rsqrtf(var + 1e-5f);
    }
    __syncthreads();
    float m = smean, r = srstd;
    for (int i = tid; i < N; i += 256) {
        if constexpr (MODE == 0) {
            // i is NCHW linear: c = i>>12, p = i&4095. g NCHW-linear = i.
            float v = ((const float*)xin)[base + i];
            int c = i >> 12, p = i & 4095;
            out[base + (size_t)p * 32 + c] = f2b((v - m) * r * g[i] + bb[i]);
        } else {
            // i is NHWC linear: p = i>>5, c = i&31. g index = c*4096 + p.
            float v = b2f(((const bf16*)xin)[base + i]);
            int p = i >> 5, c = i & 31;
            int gi = c * 4096 + p;
            out[base + i] = f2b((v - m) * r * g[gi] + bb[gi]);
        }
    }
}

// ---------------- MFMA implicit-GEMM 3x3 conv, pad 1, NHWC ----------------
// Input [sample][64][64][CI] bf16. Output positions HOxWO (WO=64/S).
// Weights packed [tap][CO_TOTAL][CI] bf16.
// Block: 4 waves; each wave owns 4 N-tiles (16 positions each) => 256 pos/block.
// EPI: 1 plain -> NHWC bf16
//      2 +bias + NCHW f32 residual -> NHWC bf16
//      3 +bias + GELU -> NHWC bf16
//      4 +bias + NHWC bf16 residual -> NCHW f32
template <int CI, int CI_BLK, int CO_TOTAL, int CO_BLK, int S, int EPI>
__global__ __launch_bounds__(256) void conv_mfma(const bf16* __restrict__ in,
                                                 const bf16* __restrict__ wpk,
                                                 const float* __restrict__ bias,
                                                 const void* __restrict__ res,
                                                 void* __restrict__ out,
                                                 int in_s0, int out_s0) {
    constexpr int WO = 64 / S;
    constexpr int HO = 64 / S;
    constexpr int NG = (HO * WO) / 256;       // n-groups per sample
    constexpr int TPR = WO / 16;              // tiles per output row
    constexpr int MT = CO_BLK / 16;
    constexpr int PHASES = CI / CI_BLK;
    constexpr int KC = CI_BLK / 32;           // k-chunks (32 each) per phase
    constexpr int PAD = CI_BLK + 8;           // LDS row stride (bank-aliasing <=2-way)

    __shared__ short s_w[9 * CO_BLK * PAD];

    const int tid = threadIdx.x;
    const int lane = tid & 63;
    const int wv = tid >> 6;
    const int quad = lane >> 4;
    const int n16 = lane & 15;

    const int ng = blockIdx.x % NG;
    const int cg = blockIdx.x / NG;
    const int co0 = cg * CO_BLK;
    const int smp = blockIdx.y;

    f32x4 acc[MT][4];
#pragma unroll
    for (int mt = 0; mt < MT; ++mt)
#pragma unroll
        for (int j = 0; j < 4; ++j) acc[mt][j] = (f32x4){0.f, 0.f, 0.f, 0.f};

    const size_t in_base = (size_t)(in_s0 + smp) * 4096 * CI;

    for (int phase = 0; phase < PHASES; ++phase) {
        const int ci0 = phase * CI_BLK;
        __syncthreads();
        // stage weights [tap][CO_BLK][CI_BLK] -> s_w padded
        for (int idx = tid; idx < 9 * CO_BLK * CI_BLK / 4; idx += 256) {
            int e = idx * 4;
            int tap = e / (CO_BLK * CI_BLK);
            int rem = e - tap * (CO_BLK * CI_BLK);
            int col = rem / CI_BLK;
            int k = rem - col * CI_BLK;
            const ushort4 src = *(const ushort4*)&wpk[((size_t)tap * CO_TOTAL + co0 + col) * CI + ci0 + k];
            *(ushort4*)&s_w[(tap * CO_BLK + col) * PAD + k] = src;
        }
        __syncthreads();

#pragma unroll
        for (int ky = 0; ky < 3; ++ky) {
#pragma unroll
            for (int kx = 0; kx < 3; ++kx) {
                const int tap = ky * 3 + kx;
                bf16x8 bfrag[KC][4];
#pragma unroll
                for (int kc = 0; kc < KC; ++kc) {
#pragma unroll
                    for (int j = 0; j < 4; ++j) {
                        int tile = ng * 16 + wv * 4 + j;
                        int yo = tile / TPR;
                        int xo = (tile % TPR) * 16;
                        int xi = (xo + n16) * S + kx - 1;
                        int yi = yo * S + ky - 1;
                        bool valid = (xi >= 0) && (xi < 64) && (yi >= 0) && (yi < 64);
                        uint4 u;
                        if (valid)
                            u = *(const uint4*)&in[in_base + ((size_t)yi * 64 + xi) * CI + ci0 + kc * 32 + quad * 8];
                        else
                            u = make_uint4(0u, 0u, 0u, 0u);
                        __builtin_memcpy(&bfrag[kc][j], &u, 16);
                    }
                }
#pragma unroll
                for (int kc = 0; kc < KC; ++kc) {
#pragma unroll
                    for (int mt = 0; mt < MT; ++mt) {
                        bf16x8 afrag = *(const bf16x8*)&s_w[(tap * CO_BLK + mt * 16 + n16) * PAD + kc * 32 + quad * 8];
#pragma unroll
                        for (int j = 0; j < 4; ++j)
                            acc[mt][j] = __builtin_amdgcn_mfma_f32_16x16x32_bf16(afrag, bfrag[kc][j], acc[mt][j], 0, 0, 0);
                    }
                }
            }
        }
    }

    // epilogue: D row(m) = quad*4 + reg, col(n) = n16
    const int osmp = out_s0 + smp;
#pragma unroll
    for (int j = 0; j < 4; ++j) {
        int tile = ng * 16 + wv * 4 + j;
        int yo = tile / TPR;
        int xo = (tile % TPR) * 16;
        int pos = yo * WO + xo + n16;
#pragma unroll
        for (int mt = 0; mt < MT; ++mt) {
            int coutb = co0 + mt * 16 + quad * 4;
            float b0 = 0.f, b1 = 0.f, b2 = 0.f, b3 = 0.f;
            if constexpr (EPI != 1) {
                float4 bv = *(const float4*)&bias[coutb];
                b0 = bv.x; b1 = bv.y; b2 = bv.z; b3 = bv.w;
            }
            float v0 = acc[mt][j][0] + b0;
            float v1 = acc[mt][j][1] + b1;
            float v2 = acc[mt][j][2] + b2;
            float v3 = acc[mt][j][3] + b3;
            if constexpr (EPI == 1 || EPI == 2 || EPI == 3) {
                if constexpr (EPI == 2) {
                    const float* xr = (const float*)res + (size_t)osmp * 131072 + (size_t)coutb * 4096 + pos;
                    v0 += xr[0]; v1 += xr[4096]; v2 += xr[8192]; v3 += xr[12288];
                } else if constexpr (EPI == 3) {
                    v0 = gelu_new(v0); v1 = gelu_new(v1); v2 = gelu_new(v2); v3 = gelu_new(v3);
                }
                ushort4 st;
                st.x = f2bu(v0); st.y = f2bu(v1); st.z = f2bu(v2); st.w = f2bu(v3);
                *(ushort4*)&((bf16*)out)[((size_t)osmp * HO * WO + pos) * CO_TOTAL + coutb] = st;
            } else {  // EPI 4: + NHWC bf16 residual -> NCHW f32
                ushort4 rv = *(const ushort4*)&((const bf16*)res)[((size_t)osmp * 4096 + pos) * 32 + coutb];
                v0 += su2f(rv.x); v1 += su2f(rv.y); v2 += su2f(rv.z); v3 += su2f(rv.w);
                float* op = (float*)out + (size_t)osmp * 131072 + (size_t)coutb * 4096 + pos;
                op[0] = v0; op[4096] = v1; op[8192] = v2; op[12288] = v3;
            }
        }
    }
}

// ---------------- attention: scores + softmax (NHWC heads) ----------------
// Q,K: [128][1024][32] bf16 NHWC. Head h = channels [h*4, h*4+4).
// att [b][h][t][s] f32. One block per (b,h,t).
__global__ __launch_bounds__(256) void attn_scores_k(const bf16* __restrict__ Q,
                                                     const bf16* __restrict__ K,
                                                     float* __restrict__ att) {
    __shared__ float s_q[4096];
    __shared__ float rs[256];
    __shared__ float s_att[32];
    const int tid = threadIdx.x;
    const int t = blockIdx.x & 31;
    const int h = (blockIdx.x >> 5) & 7;
    const int b = blockIdx.x >> 8;

    const bf16* qrow = Q + (size_t)(b * 32 + t) * 32768 + h * 4;
    for (int i = tid; i < 4096; i += 256) {
        int p = i >> 2, cl = i & 3;
        s_q[i] = b2f(qrow[(size_t)p * 32 + cl]);
    }
    __syncthreads();

    for (int s = 0; s < 32; ++s) {
        const bf16* krow = K + (size_t)(b * 32 + s) * 32768 + h * 4;
        float p = 0.f;
        for (int d = tid; d < 4096; d += 256) {
            int pp = d >> 2, cl = d & 3;
            p += s_q[d] * b2f(krow[(size_t)pp * 32 + cl]);
        }
        rs[tid] = p;
        __syncthreads();
        for (int off = 128; off > 0; off >>= 1) {
            if (tid < off) rs[tid] += rs[tid + off];
            __syncthreads();
        }
        if (tid == 0) s_att[s] = rs[0] * (1.0f / 64.0f);
        __syncthreads();
    }
    if (tid == 0) {
        float mx = -1e30f;
        for (int i = 0; i < 32; ++i) mx = fmaxf(mx, s_att[i]);
        float sum = 0.f;
        for (int i = 0; i < 32; ++i) { s_att[i] = expf(s_att[i] - mx); sum += s_att[i]; }
        float inv = 1.f / sum;
        for (int i = 0; i < 32; ++i) att[(size_t)blockIdx.x * 32 + i] = s_att[i] * inv;
    }
}

// ---------------- y = att @ v (NHWC) ----------------
// One thread per (b,t,p,c); head h = c>>2. V,Y [128][4096][32] bf16.
__global__ __launch_bounds__(256) void attn_apply_k(const float* __restrict__ att,
                                                    const bf16* __restrict__ V,
                                                    bf16* __restrict__ Y) {
    int gid = blockIdx.x * 256 + threadIdx.x;   // 2^24 threads
    int c = gid & 31;
    int p = (gid >> 5) & 4095;
    int t = (gid >> 17) & 31;
    int b = gid >> 22;
    int h = c >> 2;
    const float* arow = att + (size_t)(((b * 8 + h) * 32 + t) * 32);
    float acc = 0.f;
    for (int s = 0; s < 32; ++s)
        acc += arow[s] * b2f(V[((size_t)(b * 32 + s) * 4096 + p) * 32 + c]);
    Y[((size_t)(b * 32 + t) * 4096 + p) * 32 + c] = f2b(acc);
}

extern "C" void kernel_launch(void* const* d_in, const int* in_sizes, int n_in,
                              void* d_out, int out_size, void* d_ws, size_t ws_size,
                              hipStream_t stream) {
    const float* x   = (const float*)d_in[0];
    const float* n1g = (const float*)d_in[1];
    const float* n1b = (const float*)d_in[2];
    const float* n2g = (const float*)d_in[3];
    const float* n2b = (const float*)d_in[4];
    const float* Wk  = (const float*)d_in[5];
    const float* Wq  = (const float*)d_in[6];
    const float* Wv  = (const float*)d_in[7];
    const float* Wo  = (const float*)d_in[8];
    const float* bo  = (const float*)d_in[9];
    const float* Wm1 = (const float*)d_in[10];
    const float* bm1 = (const float*)d_in[11];
    const float* Wm2 = (const float*)d_in[12];
    const float* bm2 = (const float*)d_in[13];

    char* ws = (char*)d_ws;
    // Region layout (bytes), all NHWC:
    //  A [0, 33.5M):        xn -> Y -> xn2      (bf16 [128][4096][32])
    //  B [33.5M, 67.1M):    V  -> X1            (bf16 [128][4096][32])
    //  D [67.1M, +128K):    att                 (f32 [4][8][32][32])
    //  E [67.24M, +222K):   packed weights      (bf16)
    //  C [67.46M, ws_end):  K(8.4M), Q(8.4M) -> Hb (bf16 [chunk][4096][128])
    const size_t A_OFF = 0;
    const size_t B_OFF = 33554432;
    const size_t D_OFF = 67108864;
    const size_t E_OFF = 67239936;
    const size_t C_OFF = 67461120;
    const size_t Q_OFF = C_OFF + 8388608;

    bf16*  xn   = (bf16*)(ws + A_OFF);
    bf16*  Yb   = (bf16*)(ws + A_OFF);
    bf16*  xn2  = (bf16*)(ws + A_OFF);
    bf16*  Vb   = (bf16*)(ws + B_OFF);
    bf16*  X1   = (bf16*)(ws + B_OFF);
    float* attb = (float*)(ws + D_OFF);
    bf16*  wpk_k  = (bf16*)(ws + E_OFF);            // 18432 B each (32x32x9)
    bf16*  wpk_q  = (bf16*)(ws + E_OFF + 18432);
    bf16*  wpk_v  = (bf16*)(ws + E_OFF + 36864);
    bf16*  wpk_o  = (bf16*)(ws + E_OFF + 55296);
    bf16*  wpk_m1 = (bf16*)(ws + E_OFF + 73728);    // 73728 B (128x32x9)
    bf16*  wpk_m2 = (bf16*)(ws + E_OFF + 147456);   // 73728 B (32x128x9)
    bf16*  Kb   = (bf16*)(ws + C_OFF);
    bf16*  Qb   = (bf16*)(ws + Q_OFF);
    bf16*  Hb   = (bf16*)(ws + C_OFF);              // overwrites K/Q after attention

    // Hb chunking: per-sample h is 128*4096 bf16 = 1 MiB.
    const size_t HB_PER_SAMPLE = 1048576;
    int chunk = 128;
    if (ws_size < C_OFF + 128 * HB_PER_SAMPLE) {
        size_t avail = (ws_size > C_OFF) ? (ws_size - C_OFF) : HB_PER_SAMPLE;
        chunk = (int)(avail / HB_PER_SAMPLE);
        if (chunk < 1) chunk = 1;
        if (chunk > 128) chunk = 128;
    }

    // 0. pack weights to [tap][O][I] bf16
    pack_w<<<36, 256, 0, stream>>>(Wk, wpk_k, 32, 32);
    pack_w<<<36, 256, 0, stream>>>(Wq, wpk_q, 32, 32);
    pack_w<<<36, 256, 0, stream>>>(Wv, wpk_v, 32, 32);
    pack_w<<<36, 256, 0, stream>>>(Wo, wpk_o, 32, 32);
    pack_w<<<144, 256, 0, stream>>>(Wm1, wpk_m1, 128, 32);
    pack_w<<<144, 256, 0, stream>>>(Wm2, wpk_m2, 32, 128);

    // 1. LN1: x (NCHW f32) -> xn (NHWC bf16)
    ln_kernel<0><<<128, 256, 0, stream>>>(x, n1g, n1b, xn);
    // 2-4. k,q (stride 2, NG=4), v (stride 1, NG=16)
    conv_mfma<32, 32, 32, 32, 2, 1><<<dim3(4, 128), 256, 0, stream>>>(xn, wpk_k, nullptr, nullptr, Kb, 0, 0);
    conv_mfma<32, 32, 32, 32, 2, 1><<<dim3(4, 128), 256, 0, stream>>>(xn, wpk_q, nullptr, nullptr, Qb, 0, 0);
    conv_mfma<32, 32, 32, 32, 1, 1><<<dim3(16, 128), 256, 0, stream>>>(xn, wpk_v, nullptr, nullptr, Vb, 0, 0);
    // 5. attention scores + softmax
    attn_scores_k<<<1024, 256, 0, stream>>>(Qb, Kb, attb);
    // 6. y = att @ v  (Y overwrites xn — dead)
    attn_apply_k<<<65536, 256, 0, stream>>>(attb, Vb, Yb);
    // 7. Wo conv + bias + residual x (NCHW f32) -> X1 (NHWC bf16; overwrites V)
    conv_mfma<32, 32, 32, 32, 1, 2><<<dim3(16, 128), 256, 0, stream>>>(Yb, wpk_o, bo, x, X1, 0, 0);
    // 8. LN2: X1 -> xn2 (overwrites Y — dead)
    ln_kernel<1><<<128, 256, 0, stream>>>(X1, n2g, n2b, xn2);
    // 9-10. mixer, chunked over samples; final write NCHW f32 to d_out.
    for (int s0 = 0; s0 < 128; s0 += chunk) {
        int n = (128 - s0 < chunk) ? (128 - s0) : chunk;
        conv_mfma<32, 32, 128, 64, 1, 3><<<dim3(32, n), 256, 0, stream>>>(xn2, wpk_m1, bm1, nullptr, Hb, s0, 0);
        conv_mfma<128, 64, 32, 32, 1, 4><<<dim3(16, n), 256, 0, stream>>>(Hb, wpk_m2, bm2, X1, (float*)d_out, 0, s0);
    }
}

// Round 7
// 778.323 us; speedup vs baseline: 5.1212x; 2.0622x over previous
//
#include <hip/hip_runtime.h>
#include <hip/hip_bf16.h>

using bf16 = __hip_bfloat16;
typedef short bf16x8 __attribute__((ext_vector_type(8)));
typedef float f32x4 __attribute__((ext_vector_type(4)));

__device__ inline float b2f(bf16 h) { return __bfloat162float(h); }
__device__ inline bf16 f2b(float f) { return __float2bfloat16(f); }
__device__ inline unsigned short f2bu(float f) {
    bf16 h = __float2bfloat16(f);
    unsigned short u;
    __builtin_memcpy(&u, &h, 2);
    return u;
}
__device__ inline float su2f(unsigned short u) {  // bf16 bits -> float
    unsigned v = ((unsigned)u) << 16;
    return __uint_as_float(v);
}
__device__ inline float gelu_new(float x) {
    float x3 = x * x * x;
    return 0.5f * x * (1.0f + tanhf(0.7978845608028654f * (x + 0.044715f * x3)));
}

// ---------------- weight pack: [O][I][3][3] f32 -> [tap][O][I] bf16 ----------
__global__ __launch_bounds__(256) void pack_w(const float* __restrict__ w,
                                              bf16* __restrict__ wpk,
                                              int CO, int CI) {
    int i = blockIdx.x * 256 + threadIdx.x;
    int total = CO * CI * 9;
    if (i < total) {
        int tap = i % 9;
        int ci = (i / 9) % CI;
        int co = i / (9 * CI);
        wpk[((size_t)tap * CO + co) * CI + ci] = f2b(w[i]);
    }
}

// ---------------- g/b transpose NCHW f32 -> NHWC f32 (two arrays) -----------
__global__ __launch_bounds__(256) void gtrans_k(const float* __restrict__ g,
                                                const float* __restrict__ bb,
                                                float* __restrict__ gt,
                                                float* __restrict__ bt) {
    int i = blockIdx.x * 256 + threadIdx.x;   // 262144 total
    int sel = i >> 17;
    int o = i & 131071;          // NHWC linear out index
    int p = o >> 5, c = o & 31;
    int src = c * 4096 + p;      // NCHW
    if (sel == 0) gt[o] = g[src];
    else          bt[o] = bb[src];
}

// ---------------- LN partial reduce: grid (8, 128) ----------------
template <typename TIN>
__global__ __launch_bounds__(256) void ln_part(const void* __restrict__ xin,
                                               float2* __restrict__ spart) {
    const int tid = threadIdx.x;
    const int sample = blockIdx.y, seg = blockIdx.x;
    const size_t base = (size_t)sample * 131072 + seg * 16384;
    float sum = 0.f, ss = 0.f;
    if constexpr (sizeof(TIN) == 4) {
        const float4* p = (const float4*)((const float*)xin + base);
        for (int l = 0; l < 16; ++l) {
            float4 v = p[l * 256 + tid];
            sum += v.x + v.y + v.z + v.w;
            ss += v.x * v.x + v.y * v.y + v.z * v.z + v.w * v.w;
        }
    } else {
        const uint4* p = (const uint4*)((const bf16*)xin + base);
        for (int l = 0; l < 8; ++l) {
            uint4 u = p[l * 256 + tid];
            unsigned w[4] = {u.x, u.y, u.z, u.w};
#pragma unroll
            for (int j = 0; j < 4; ++j) {
                float lo = __uint_as_float(w[j] << 16);
                float hi = __uint_as_float(w[j] & 0xffff0000u);
                sum += lo + hi;
                ss += lo * lo + hi * hi;
            }
        }
    }
    __shared__ float rs[256], rs2[256];
    rs[tid] = sum; rs2[tid] = ss;
    __syncthreads();
    for (int off = 128; off > 0; off >>= 1) {
        if (tid < off) { rs[tid] += rs[tid + off]; rs2[tid] += rs2[tid + off]; }
        __syncthreads();
    }
    if (tid == 0) spart[sample * 8 + seg] = make_float2(rs[0], rs2[0]);
}

// ---------------- LN finalize: 1 block, 128 threads ----------------
__global__ __launch_bounds__(128) void ln_fin(const float2* __restrict__ spart,
                                              float2* __restrict__ stats) {
    int t = threadIdx.x;
    float s = 0.f, ss = 0.f;
    for (int j = 0; j < 8; ++j) {
        float2 v = spart[t * 8 + j];
        s += v.x; ss += v.y;
    }
    float m = s / 131072.f;
    float var = ss / 131072.f - m * m;
    stats[t] = make_float2(m, rsqrtf(var + 1e-5f));
}

// ---------------- LN1 normalize + NCHW->NHWC transpose ----------------
// grid (32, 128): sample = by, p-tile (128 positions) = bx.
__global__ __launch_bounds__(256) void ln1_norm_t(const float* __restrict__ x,
                                                  const float* __restrict__ g,
                                                  const float* __restrict__ bb,
                                                  const float2* __restrict__ stats,
                                                  bf16* __restrict__ out) {
    __shared__ float tile[32][129];
    const int tid = threadIdx.x;
    const int sample = blockIdx.y;
    const int p0 = blockIdx.x * 128;
    float2 st = stats[sample];
    const float m = st.x, r = st.y;
    const size_t xb = (size_t)sample * 131072;
    for (int k = 0; k < 16; ++k) {
        int idx = k * 256 + tid;           // 4096 = 32c x 128p
        int c = idx >> 7, p = idx & 127;
        int gi = c * 4096 + p0 + p;
        float v = x[xb + gi];
        tile[c][p] = (v - m) * r * g[gi] + bb[gi];
    }
    __syncthreads();
    for (int k = 0; k < 8; ++k) {
        int idx = k * 256 + tid;           // 2048 = 128p x 16 c-pairs
        int p = idx >> 4, c2 = (idx & 15) * 2;
        unsigned lo = (unsigned)f2bu(tile[c2][p]);
        unsigned hi = (unsigned)f2bu(tile[c2 + 1][p]);
        *(unsigned*)&out[xb + (size_t)(p0 + p) * 32 + c2] = lo | (hi << 16);
    }
}

// ---------------- LN2 normalize, NHWC linear ----------------
// grid (64, 128); gt/bt are NHWC f32.
__global__ __launch_bounds__(256) void ln2_norm(const bf16* __restrict__ xin,
                                                const float* __restrict__ gt,
                                                const float* __restrict__ bt,
                                                const float2* __restrict__ stats,
                                                bf16* __restrict__ out) {
    const int tid = threadIdx.x;
    const int sample = blockIdx.y;
    float2 st = stats[sample];
    const float m = st.x, r = st.y;
    int i0 = (blockIdx.x * 256 + tid) * 8;       // within sample [0, 131072)
    const size_t base = (size_t)sample * 131072 + i0;
    uint4 u = *(const uint4*)&xin[base];
    float4 g0 = *(const float4*)&gt[i0];
    float4 g1 = *(const float4*)&gt[i0 + 4];
    float4 b0 = *(const float4*)&bt[i0];
    float4 b1 = *(const float4*)&bt[i0 + 4];
    unsigned w[4] = {u.x, u.y, u.z, u.w};
    float gv[8] = {g0.x, g0.y, g0.z, g0.w, g1.x, g1.y, g1.z, g1.w};
    float bv[8] = {b0.x, b0.y, b0.z, b0.w, b1.x, b1.y, b1.z, b1.w};
    unsigned o[4];
#pragma unroll
    for (int j = 0; j < 4; ++j) {
        float lo = __uint_as_float(w[j] << 16);
        float hi = __uint_as_float(w[j] & 0xffff0000u);
        lo = (lo - m) * r * gv[2 * j] + bv[2 * j];
        hi = (hi - m) * r * gv[2 * j + 1] + bv[2 * j + 1];
        o[j] = (unsigned)f2bu(lo) | ((unsigned)f2bu(hi) << 16);
    }
    uint4 st4 = make_uint4(o[0], o[1], o[2], o[3]);
    *(uint4*)&out[base] = st4;
}

// ---------------- MFMA implicit-GEMM 3x3 conv, pad 1, NHWC ----------------
// (unchanged from round 6 — verified correct)
template <int CI, int CI_BLK, int CO_TOTAL, int CO_BLK, int S, int EPI>
__global__ __launch_bounds__(256) void conv_mfma(const bf16* __restrict__ in,
                                                 const bf16* __restrict__ wpk,
                                                 const float* __restrict__ bias,
                                                 const void* __restrict__ res,
                                                 void* __restrict__ out,
                                                 int in_s0, int out_s0) {
    constexpr int WO = 64 / S;
    constexpr int HO = 64 / S;
    constexpr int NG = (HO * WO) / 256;
    constexpr int TPR = WO / 16;
    constexpr int MT = CO_BLK / 16;
    constexpr int PHASES = CI / CI_BLK;
    constexpr int KC = CI_BLK / 32;
    constexpr int PAD = CI_BLK + 8;

    __shared__ short s_w[9 * CO_BLK * PAD];

    const int tid = threadIdx.x;
    const int lane = tid & 63;
    const int wv = tid >> 6;
    const int quad = lane >> 4;
    const int n16 = lane & 15;

    const int ng = blockIdx.x % NG;
    const int cg = blockIdx.x / NG;
    const int co0 = cg * CO_BLK;
    const int smp = blockIdx.y;

    f32x4 acc[MT][4];
#pragma unroll
    for (int mt = 0; mt < MT; ++mt)
#pragma unroll
        for (int j = 0; j < 4; ++j) acc[mt][j] = (f32x4){0.f, 0.f, 0.f, 0.f};

    const size_t in_base = (size_t)(in_s0 + smp) * 4096 * CI;

    for (int phase = 0; phase < PHASES; ++phase) {
        const int ci0 = phase * CI_BLK;
        __syncthreads();
        for (int idx = tid; idx < 9 * CO_BLK * CI_BLK / 4; idx += 256) {
            int e = idx * 4;
            int tap = e / (CO_BLK * CI_BLK);
            int rem = e - tap * (CO_BLK * CI_BLK);
            int col = rem / CI_BLK;
            int k = rem - col * CI_BLK;
            const ushort4 src = *(const ushort4*)&wpk[((size_t)tap * CO_TOTAL + co0 + col) * CI + ci0 + k];
            *(ushort4*)&s_w[(tap * CO_BLK + col) * PAD + k] = src;
        }
        __syncthreads();

#pragma unroll
        for (int ky = 0; ky < 3; ++ky) {
#pragma unroll
            for (int kx = 0; kx < 3; ++kx) {
                const int tap = ky * 3 + kx;
                bf16x8 bfrag[KC][4];
#pragma unroll
                for (int kc = 0; kc < KC; ++kc) {
#pragma unroll
                    for (int j = 0; j < 4; ++j) {
                        int tile = ng * 16 + wv * 4 + j;
                        int yo = tile / TPR;
                        int xo = (tile % TPR) * 16;
                        int xi = (xo + n16) * S + kx - 1;
                        int yi = yo * S + ky - 1;
                        bool valid = (xi >= 0) && (xi < 64) && (yi >= 0) && (yi < 64);
                        uint4 u;
                        if (valid)
                            u = *(const uint4*)&in[in_base + ((size_t)yi * 64 + xi) * CI + ci0 + kc * 32 + quad * 8];
                        else
                            u = make_uint4(0u, 0u, 0u, 0u);
                        __builtin_memcpy(&bfrag[kc][j], &u, 16);
                    }
                }
#pragma unroll
                for (int kc = 0; kc < KC; ++kc) {
#pragma unroll
                    for (int mt = 0; mt < MT; ++mt) {
                        bf16x8 afrag = *(const bf16x8*)&s_w[(tap * CO_BLK + mt * 16 + n16) * PAD + kc * 32 + quad * 8];
#pragma unroll
                        for (int j = 0; j < 4; ++j)
                            acc[mt][j] = __builtin_amdgcn_mfma_f32_16x16x32_bf16(afrag, bfrag[kc][j], acc[mt][j], 0, 0, 0);
                    }
                }
            }
        }
    }

    const int osmp = out_s0 + smp;
#pragma unroll
    for (int j = 0; j < 4; ++j) {
        int tile = ng * 16 + wv * 4 + j;
        int yo = tile / TPR;
        int xo = (tile % TPR) * 16;
        int pos = yo * WO + xo + n16;
#pragma unroll
        for (int mt = 0; mt < MT; ++mt) {
            int coutb = co0 + mt * 16 + quad * 4;
            float b0 = 0.f, b1 = 0.f, b2 = 0.f, b3 = 0.f;
            if constexpr (EPI != 1) {
                float4 bv = *(const float4*)&bias[coutb];
                b0 = bv.x; b1 = bv.y; b2 = bv.z; b3 = bv.w;
            }
            float v0 = acc[mt][j][0] + b0;
            float v1 = acc[mt][j][1] + b1;
            float v2 = acc[mt][j][2] + b2;
            float v3 = acc[mt][j][3] + b3;
            if constexpr (EPI == 1 || EPI == 2 || EPI == 3) {
                if constexpr (EPI == 2) {
                    const float* xr = (const float*)res + (size_t)osmp * 131072 + (size_t)coutb * 4096 + pos;
                    v0 += xr[0]; v1 += xr[4096]; v2 += xr[8192]; v3 += xr[12288];
                } else if constexpr (EPI == 3) {
                    v0 = gelu_new(v0); v1 = gelu_new(v1); v2 = gelu_new(v2); v3 = gelu_new(v3);
                }
                ushort4 st;
                st.x = f2bu(v0); st.y = f2bu(v1); st.z = f2bu(v2); st.w = f2bu(v3);
                *(ushort4*)&((bf16*)out)[((size_t)osmp * HO * WO + pos) * CO_TOTAL + coutb] = st;
            } else {
                ushort4 rv = *(const ushort4*)&((const bf16*)res)[((size_t)osmp * 4096 + pos) * 32 + coutb];
                v0 += su2f(rv.x); v1 += su2f(rv.y); v2 += su2f(rv.z); v3 += su2f(rv.w);
                float* op = (float*)out + (size_t)osmp * 131072 + (size_t)coutb * 4096 + pos;
                op[0] = v0; op[4096] = v1; op[8192] = v2; op[12288] = v3;
            }
        }
    }
}

// ---------------- attention: scores + softmax (bf16 output) ----------------
// Q,K: [128][1024][32] bf16 NHWC. att [b][h][t][s] bf16. Block per (b,h,t).
__global__ __launch_bounds__(256) void attn_scores_k(const bf16* __restrict__ Q,
                                                     const bf16* __restrict__ K,
                                                     bf16* __restrict__ att) {
    __shared__ float s_q[4096];
    __shared__ float rs[256];
    __shared__ float s_att[32];
    const int tid = threadIdx.x;
    const int t = blockIdx.x & 31;
    const int h = (blockIdx.x >> 5) & 7;
    const int b = blockIdx.x >> 8;

    const bf16* qrow = Q + (size_t)(b * 32 + t) * 32768 + h * 4;
    for (int i = tid; i < 4096; i += 256) {
        int p = i >> 2, cl = i & 3;
        s_q[i] = b2f(qrow[(size_t)p * 32 + cl]);
    }
    __syncthreads();

    for (int s = 0; s < 32; ++s) {
        const bf16* krow = K + (size_t)(b * 32 + s) * 32768 + h * 4;
        float p = 0.f;
        for (int d = tid; d < 4096; d += 256) {
            int pp = d >> 2, cl = d & 3;
            p += s_q[d] * b2f(krow[(size_t)pp * 32 + cl]);
        }
        rs[tid] = p;
        __syncthreads();
        for (int off = 128; off > 0; off >>= 1) {
            if (tid < off) rs[tid] += rs[tid + off];
            __syncthreads();
        }
        if (tid == 0) s_att[s] = rs[0] * (1.0f / 64.0f);
        __syncthreads();
    }
    if (tid == 0) {
        float mx = -1e30f;
        for (int i = 0; i < 32; ++i) mx = fmaxf(mx, s_att[i]);
        float sum = 0.f;
        for (int i = 0; i < 32; ++i) { s_att[i] = expf(s_att[i] - mx); sum += s_att[i]; }
        float inv = 1.f / sum;
        for (int i = 0; i < 32; ++i) att[(size_t)blockIdx.x * 32 + i] = f2b(s_att[i] * inv);
    }
}

// ---------------- y = att @ v : MFMA with fused in-LDS V transpose ----------
// grid (256, 4): p-tile (16 positions) = bx, batch b = by. Block 256 threads.
// V NHWC [b*32+s][4096 p][32 c]; att bf16 [b][h][t][s]; Y NHWC bf16.
__global__ __launch_bounds__(256) void attn_apply_mfma(const bf16* __restrict__ att,
                                                       const bf16* __restrict__ V,
                                                       bf16* __restrict__ Y) {
    __shared__ short vlds[512 * 40];   // [h8][p16][cl4][s32 pad40]
    __shared__ short ylds[32 * 512];   // [t32][p16 x c32]
    const int tid = threadIdx.x;
    const int lane = tid & 63;
    const int wv = tid >> 6;
    const int quad = lane >> 4;
    const int n16 = lane & 15;
    const int pb = blockIdx.x;         // p-tile
    const int b = blockIdx.y;

    // stage V[s][p16][c32] -> vlds[(h*16+p)*4+cl][s]
    for (int l = 0; l < 8; ++l) {
        int u = l * 256 + tid;             // 2048 uint4
        int s = u >> 6;
        int col8 = (u & 63) * 8;
        uint4 v = *(const uint4*)&V[(((size_t)(b * 32 + s) * 4096 + pb * 16) * 32) + col8];
        unsigned short us[8];
        __builtin_memcpy(us, &v, 16);
#pragma unroll
        for (int j = 0; j < 8; ++j) {
            int idx = col8 + j;
            int p = idx >> 5, c = idx & 31;
            int row = ((c >> 2) * 16 + p) * 4 + (c & 3);
            vlds[row * 40 + s] = (short)us[j];
        }
    }
    __syncthreads();

    // MFMA: per wave, n-tile = 16 rows [wv*16 .. wv*16+16) within each h
    const int e = wv * 16 + n16;
    const int p = e >> 2, cl = e & 3;
    for (int h = 0; h < 8; ++h) {
        bf16x8 bfrag = *(const bf16x8*)&vlds[(h * 64 + e) * 40 + quad * 8];
        const int c = h * 4 + cl;
#pragma unroll
        for (int mt = 0; mt < 2; ++mt) {
            bf16x8 afrag = *(const bf16x8*)&att[((size_t)(b * 8 + h) * 32 + mt * 16 + n16) * 32 + quad * 8];
            f32x4 d = __builtin_amdgcn_mfma_f32_16x16x32_bf16(afrag, bfrag,
                                                              (f32x4){0.f, 0.f, 0.f, 0.f}, 0, 0, 0);
#pragma unroll
            for (int r = 0; r < 4; ++r) {
                int t = mt * 16 + quad * 4 + r;
                ylds[t * 512 + p * 32 + c] = (short)f2bu(d[r]);
            }
        }
    }
    __syncthreads();

    // write Y: 32 t x (16p x 32c = 1 KB contiguous)
    for (int l = 0; l < 8; ++l) {
        int u = l * 256 + tid;             // 2048 uint4
        int t = u >> 6;
        int col8 = (u & 63) * 8;
        *(uint4*)&Y[(((size_t)(b * 32 + t) * 4096 + pb * 16) * 32) + col8] =
            *(const uint4*)&ylds[t * 512 + col8];
    }
}

extern "C" void kernel_launch(void* const* d_in, const int* in_sizes, int n_in,
                              void* d_out, int out_size, void* d_ws, size_t ws_size,
                              hipStream_t stream) {
    const float* x   = (const float*)d_in[0];
    const float* n1g = (const float*)d_in[1];
    const float* n1b = (const float*)d_in[2];
    const float* n2g = (const float*)d_in[3];
    const float* n2b = (const float*)d_in[4];
    const float* Wk  = (const float*)d_in[5];
    const float* Wq  = (const float*)d_in[6];
    const float* Wv  = (const float*)d_in[7];
    const float* Wo  = (const float*)d_in[8];
    const float* bo  = (const float*)d_in[9];
    const float* Wm1 = (const float*)d_in[10];
    const float* bm1 = (const float*)d_in[11];
    const float* Wm2 = (const float*)d_in[12];
    const float* bm2 = (const float*)d_in[13];

    char* ws = (char*)d_ws;
    // Region layout (bytes), activations NHWC:
    //  A [0, 33.5M):     xn -> Y -> xn2      (bf16 [128][4096][32])
    //  B [33.5M, 67.1M): V  -> X1            (bf16 [128][4096][32])
    //  D [67.1M]:        att bf16 [4][8][32][32] (64 KB)
    //  E [67.24M]:       packed weights (222 KB)
    //  F [67.46M]:       g2t, b2t (f32 NHWC), spart, stats (~1.03 MB)
    //  C [68.52M, ...):  K(8.4M), Q(8.4M) -> Hb (bf16 [chunk][4096][128])
    const size_t A_OFF = 0;
    const size_t B_OFF = 33554432;
    const size_t D_OFF = 67108864;
    const size_t E_OFF = 67239936;
    const size_t F_OFF = 67461120;
    const size_t C_OFF = 68519936;
    const size_t Q_OFF = C_OFF + 8388608;

    bf16*  xn   = (bf16*)(ws + A_OFF);
    bf16*  Yb   = (bf16*)(ws + A_OFF);
    bf16*  xn2  = (bf16*)(ws + A_OFF);
    bf16*  Vb   = (bf16*)(ws + B_OFF);
    bf16*  X1   = (bf16*)(ws + B_OFF);
    bf16*  attbf = (bf16*)(ws + D_OFF);
    bf16*  wpk_k  = (bf16*)(ws + E_OFF);
    bf16*  wpk_q  = (bf16*)(ws + E_OFF + 18432);
    bf16*  wpk_v  = (bf16*)(ws + E_OFF + 36864);
    bf16*  wpk_o  = (bf16*)(ws + E_OFF + 55296);
    bf16*  wpk_m1 = (bf16*)(ws + E_OFF + 73728);
    bf16*  wpk_m2 = (bf16*)(ws + E_OFF + 147456);
    float* g2t  = (float*)(ws + F_OFF);
    float* b2t  = (float*)(ws + F_OFF + 524288);
    float2* spart = (float2*)(ws + F_OFF + 1048576);
    float2* stats = (float2*)(ws + F_OFF + 1056768);
    bf16*  Kb   = (bf16*)(ws + C_OFF);
    bf16*  Qb   = (bf16*)(ws + Q_OFF);
    bf16*  Hb   = (bf16*)(ws + C_OFF);

    const size_t HB_PER_SAMPLE = 1048576;
    int chunk = 128;
    if (ws_size < C_OFF + 128 * HB_PER_SAMPLE) {
        size_t avail = (ws_size > C_OFF) ? (ws_size - C_OFF) : HB_PER_SAMPLE;
        chunk = (int)(avail / HB_PER_SAMPLE);
        if (chunk < 1) chunk = 1;
        if (chunk > 128) chunk = 128;
    }

    // 0. pack weights; transpose LN2 gamma/beta to NHWC f32
    pack_w<<<36, 256, 0, stream>>>(Wk, wpk_k, 32, 32);
    pack_w<<<36, 256, 0, stream>>>(Wq, wpk_q, 32, 32);
    pack_w<<<36, 256, 0, stream>>>(Wv, wpk_v, 32, 32);
    pack_w<<<36, 256, 0, stream>>>(Wo, wpk_o, 32, 32);
    pack_w<<<144, 256, 0, stream>>>(Wm1, wpk_m1, 128, 32);
    pack_w<<<144, 256, 0, stream>>>(Wm2, wpk_m2, 32, 128);
    gtrans_k<<<1024, 256, 0, stream>>>(n2g, n2b, g2t, b2t);

    // 1. LN1: x (NCHW f32) -> xn (NHWC bf16)
    ln_part<float><<<dim3(8, 128), 256, 0, stream>>>(x, spart);
    ln_fin<<<1, 128, 0, stream>>>(spart, stats);
    ln1_norm_t<<<dim3(32, 128), 256, 0, stream>>>(x, n1g, n1b, stats, xn);
    // 2-4. k,q (stride 2), v (stride 1)
    conv_mfma<32, 32, 32, 32, 2, 1><<<dim3(4, 128), 256, 0, stream>>>(xn, wpk_k, nullptr, nullptr, Kb, 0, 0);
    conv_mfma<32, 32, 32, 32, 2, 1><<<dim3(4, 128), 256, 0, stream>>>(xn, wpk_q, nullptr, nullptr, Qb, 0, 0);
    conv_mfma<32, 32, 32, 32, 1, 1><<<dim3(16, 128), 256, 0, stream>>>(xn, wpk_v, nullptr, nullptr, Vb, 0, 0);
    // 5. attention scores + softmax -> bf16 att
    attn_scores_k<<<1024, 256, 0, stream>>>(Qb, Kb, attbf);
    // 6. y = att @ v (MFMA; Y overwrites xn — dead)
    attn_apply_mfma<<<dim3(256, 4), 256, 0, stream>>>(attbf, Vb, Yb);
    // 7. Wo conv + bias + residual x (NCHW f32) -> X1 (NHWC bf16; overwrites V)
    conv_mfma<32, 32, 32, 32, 1, 2><<<dim3(16, 128), 256, 0, stream>>>(Yb, wpk_o, bo, x, X1, 0, 0);
    // 8. LN2: X1 -> xn2 (overwrites Y — dead)
    ln_part<bf16><<<dim3(8, 128), 256, 0, stream>>>(X1, spart);
    ln_fin<<<1, 128, 0, stream>>>(spart, stats);
    ln2_norm<<<dim3(64, 128), 256, 0, stream>>>(X1, g2t, b2t, stats, xn2);
    // 9-10. mixer, chunked; final write NCHW f32 to d_out.
    for (int s0 = 0; s0 < 128; s0 += chunk) {
        int n = (128 - s0 < chunk) ? (128 - s0) : chunk;
        conv_mfma<32, 32, 128, 64, 1, 3><<<dim3(32, n), 256, 0, stream>>>(xn2, wpk_m1, bm1, nullptr, Hb, s0, 0);
        conv_mfma<128, 64, 32, 32, 1, 4><<<dim3(16, n), 256, 0, stream>>>(Hb, wpk_m2, bm2, X1, (float*)d_out, 0, s0);
    }
}

// Round 8
// 679.117 us; speedup vs baseline: 5.8694x; 1.1461x over previous
//
#include <hip/hip_runtime.h>
#include <hip/hip_bf16.h>

using bf16 = __hip_bfloat16;
typedef short bf16x8 __attribute__((ext_vector_type(8)));
typedef float f32x4 __attribute__((ext_vector_type(4)));

__device__ inline float b2f(bf16 h) { return __bfloat162float(h); }
__device__ inline bf16 f2b(float f) { return __float2bfloat16(f); }
__device__ inline unsigned short f2bu(float f) {
    bf16 h = __float2bfloat16(f);
    unsigned short u;
    __builtin_memcpy(&u, &h, 2);
    return u;
}
__device__ inline float su2f(unsigned short u) {
    unsigned v = ((unsigned)u) << 16;
    return __uint_as_float(v);
}
__device__ inline float gelu_new(float x) {
    float x3 = x * x * x;
    return 0.5f * x * (1.0f + tanhf(0.7978845608028654f * (x + 0.044715f * x3)));
}

// ---------------- weight pack: [O][I][3][3] f32 -> [tap][O][I] bf16 ----------
__global__ __launch_bounds__(256) void pack_w(const float* __restrict__ w,
                                              bf16* __restrict__ wpk,
                                              int CO, int CI) {
    int i = blockIdx.x * 256 + threadIdx.x;
    int total = CO * CI * 9;
    if (i < total) {
        int tap = i % 9;
        int ci = (i / 9) % CI;
        int co = i / (9 * CI);
        wpk[((size_t)tap * CO + co) * CI + ci] = f2b(w[i]);
    }
}

// ---------------- g/b transpose NCHW f32 -> NHWC f32 ----------
__global__ __launch_bounds__(256) void gtrans_k(const float* __restrict__ g,
                                                const float* __restrict__ bb,
                                                float* __restrict__ gt,
                                                float* __restrict__ bt) {
    int i = blockIdx.x * 256 + threadIdx.x;
    int sel = i >> 17;
    int o = i & 131071;
    int p = o >> 5, c = o & 31;
    int src = c * 4096 + p;
    if (sel == 0) gt[o] = g[src];
    else          bt[o] = bb[src];
}

// ---------------- LN partial reduce: grid (8, 128) ----------------
template <typename TIN>
__global__ __launch_bounds__(256) void ln_part(const void* __restrict__ xin,
                                               float2* __restrict__ spart) {
    const int tid = threadIdx.x;
    const int sample = blockIdx.y, seg = blockIdx.x;
    const size_t base = (size_t)sample * 131072 + seg * 16384;
    float sum = 0.f, ss = 0.f;
    if constexpr (sizeof(TIN) == 4) {
        const float4* p = (const float4*)((const float*)xin + base);
        for (int l = 0; l < 16; ++l) {
            float4 v = p[l * 256 + tid];
            sum += v.x + v.y + v.z + v.w;
            ss += v.x * v.x + v.y * v.y + v.z * v.z + v.w * v.w;
        }
    } else {
        const uint4* p = (const uint4*)((const bf16*)xin + base);
        for (int l = 0; l < 8; ++l) {
            uint4 u = p[l * 256 + tid];
            unsigned w[4] = {u.x, u.y, u.z, u.w};
#pragma unroll
            for (int j = 0; j < 4; ++j) {
                float lo = __uint_as_float(w[j] << 16);
                float hi = __uint_as_float(w[j] & 0xffff0000u);
                sum += lo + hi;
                ss += lo * lo + hi * hi;
            }
        }
    }
    __shared__ float rs[256], rs2[256];
    rs[tid] = sum; rs2[tid] = ss;
    __syncthreads();
    for (int off = 128; off > 0; off >>= 1) {
        if (tid < off) { rs[tid] += rs[tid + off]; rs2[tid] += rs2[tid + off]; }
        __syncthreads();
    }
    if (tid == 0) spart[sample * 8 + seg] = make_float2(rs[0], rs2[0]);
}

// ---------------- LN finalize ----------------
__global__ __launch_bounds__(128) void ln_fin(const float2* __restrict__ spart,
                                              float2* __restrict__ stats) {
    int t = threadIdx.x;
    float s = 0.f, ss = 0.f;
    for (int j = 0; j < 8; ++j) {
        float2 v = spart[t * 8 + j];
        s += v.x; ss += v.y;
    }
    float m = s / 131072.f;
    float var = ss / 131072.f - m * m;
    stats[t] = make_float2(m, rsqrtf(var + 1e-5f));
}

// ---------------- LN1 normalize + NCHW->NHWC transpose ----------------
__global__ __launch_bounds__(256) void ln1_norm_t(const float* __restrict__ x,
                                                  const float* __restrict__ g,
                                                  const float* __restrict__ bb,
                                                  const float2* __restrict__ stats,
                                                  bf16* __restrict__ out) {
    __shared__ float tile[32][129];
    const int tid = threadIdx.x;
    const int sample = blockIdx.y;
    const int p0 = blockIdx.x * 128;
    float2 st = stats[sample];
    const float m = st.x, r = st.y;
    const size_t xb = (size_t)sample * 131072;
    for (int k = 0; k < 16; ++k) {
        int idx = k * 256 + tid;
        int c = idx >> 7, p = idx & 127;
        int gi = c * 4096 + p0 + p;
        float v = x[xb + gi];
        tile[c][p] = (v - m) * r * g[gi] + bb[gi];
    }
    __syncthreads();
    for (int k = 0; k < 8; ++k) {
        int idx = k * 256 + tid;
        int p = idx >> 4, c2 = (idx & 15) * 2;
        unsigned lo = (unsigned)f2bu(tile[c2][p]);
        unsigned hi = (unsigned)f2bu(tile[c2 + 1][p]);
        *(unsigned*)&out[xb + (size_t)(p0 + p) * 32 + c2] = lo | (hi << 16);
    }
}

// ---------------- LN2 normalize, NHWC linear ----------------
__global__ __launch_bounds__(256) void ln2_norm(const bf16* __restrict__ xin,
                                                const float* __restrict__ gt,
                                                const float* __restrict__ bt,
                                                const float2* __restrict__ stats,
                                                bf16* __restrict__ out) {
    const int tid = threadIdx.x;
    const int sample = blockIdx.y;
    float2 st = stats[sample];
    const float m = st.x, r = st.y;
    int i0 = (blockIdx.x * 256 + tid) * 8;
    const size_t base = (size_t)sample * 131072 + i0;
    uint4 u = *(const uint4*)&xin[base];
    float4 g0 = *(const float4*)&gt[i0];
    float4 g1 = *(const float4*)&gt[i0 + 4];
    float4 b0 = *(const float4*)&bt[i0];
    float4 b1 = *(const float4*)&bt[i0 + 4];
    unsigned w[4] = {u.x, u.y, u.z, u.w};
    float gv[8] = {g0.x, g0.y, g0.z, g0.w, g1.x, g1.y, g1.z, g1.w};
    float bv[8] = {b0.x, b0.y, b0.z, b0.w, b1.x, b1.y, b1.z, b1.w};
    unsigned o[4];
#pragma unroll
    for (int j = 0; j < 4; ++j) {
        float lo = __uint_as_float(w[j] << 16);
        float hi = __uint_as_float(w[j] & 0xffff0000u);
        lo = (lo - m) * r * gv[2 * j] + bv[2 * j];
        hi = (hi - m) * r * gv[2 * j + 1] + bv[2 * j + 1];
        o[j] = (unsigned)f2bu(lo) | ((unsigned)f2bu(hi) << 16);
    }
    uint4 st4 = make_uint4(o[0], o[1], o[2], o[3]);
    *(uint4*)&out[base] = st4;
}

// ---------------- stride-1 conv: both operands staged in LDS ----------------
// Input NHWC [sample][64][64][CI] bf16. Block covers 4 output rows x 64 cols.
// LDS: s_in [6 rows][66 x][32 ci] + s_w [9][CO_BLK][32], both XOR-swizzled
// per 8-short sub-chunk so every ds_read_b128 / ds_write_b128 is
// bank-phase-conflict-free (sub' = sub ^ (r&3) ^ ((r>>2)&1)).
// EPI: 1 plain->NHWC bf16, 2 +bias+NCHW f32 res->NHWC bf16,
//      3 +bias+GELU->NHWC bf16, 4 +bias+NHWC bf16 res->NCHW f32
template <int CI, int CO_TOTAL, int CO_BLK, int EPI>
__global__ __launch_bounds__(256) void conv_lds(const bf16* __restrict__ in,
                                                const bf16* __restrict__ wpk,
                                                const float* __restrict__ bias,
                                                const void* __restrict__ res,
                                                void* __restrict__ out,
                                                int in_s0, int out_s0) {
    constexpr int CHUNKS = CI / 32;
    constexpr int MT = CO_BLK / 16;
    constexpr int NG = 16;

    __shared__ short s_in[6 * 66 * 32];
    __shared__ short s_w[9 * CO_BLK * 32];

    const int tid = threadIdx.x;
    const int lane = tid & 63;
    const int wv = tid >> 6;
    const int quad = lane >> 4;
    const int n16 = lane & 15;

    const int ng = blockIdx.x % NG;
    const int cg = blockIdx.x / NG;
    const int co0 = cg * CO_BLK;
    const int smp = blockIdx.y;
    const int y0 = ng * 4;

    f32x4 acc[MT][4];
#pragma unroll
    for (int mt = 0; mt < MT; ++mt)
#pragma unroll
        for (int j = 0; j < 4; ++j) acc[mt][j] = (f32x4){0.f, 0.f, 0.f, 0.f};

    const size_t in_base = (size_t)(in_s0 + smp) * 4096 * CI;

    for (int chunk = 0; chunk < CHUNKS; ++chunk) {
        const int ci0 = chunk * 32;
        __syncthreads();
        // stage input tile: 6 rows x 66 x 32ci, zero-padded, swizzled
        for (int i = tid; i < 6 * 66 * 4; i += 256) {
            int sub = i & 3;
            int x = (i >> 2) % 66;
            int row = i / 264;
            int y = y0 + row - 1;
            int xg = x - 1;
            uint4 u = make_uint4(0u, 0u, 0u, 0u);
            if (y >= 0 && y < 64 && xg >= 0 && xg < 64)
                u = *(const uint4*)&in[in_base + ((size_t)y * 64 + xg) * CI + ci0 + sub * 8];
            int ps = sub ^ (x & 3) ^ ((x >> 2) & 1);
            *(uint4*)&s_in[(row * 66 + x) * 32 + ps * 8] = u;
        }
        // stage weights: 9 taps x CO_BLK x 32ci, swizzled
        for (int i = tid; i < 9 * CO_BLK * 4; i += 256) {
            int sub = i & 3;
            int co = (i >> 2) % CO_BLK;
            int tap = i / (CO_BLK * 4);
            uint4 u = *(const uint4*)&wpk[((size_t)tap * CO_TOTAL + co0 + co) * CI + ci0 + sub * 8];
            int ps = sub ^ (co & 3) ^ ((co >> 2) & 1);
            *(uint4*)&s_w[(tap * CO_BLK + co) * 32 + ps * 8] = u;
        }
        __syncthreads();

#pragma unroll
        for (int ky = 0; ky < 3; ++ky) {
#pragma unroll
            for (int kx = 0; kx < 3; ++kx) {
                const int tap = ky * 3 + kx;
                bf16x8 bfrag[4];
#pragma unroll
                for (int j = 0; j < 4; ++j) {
                    int x = j * 16 + n16 + kx;           // staged index (x_global+1)
                    int ps = quad ^ (x & 3) ^ ((x >> 2) & 1);
                    bfrag[j] = *(const bf16x8*)&s_in[((wv + ky) * 66 + x) * 32 + ps * 8];
                }
#pragma unroll
                for (int mt = 0; mt < MT; ++mt) {
                    int mrow = mt * 16 + n16;
                    int ps = quad ^ (mrow & 3) ^ ((mrow >> 2) & 1);
                    bf16x8 afrag = *(const bf16x8*)&s_w[(tap * CO_BLK + mrow) * 32 + ps * 8];
#pragma unroll
                    for (int j = 0; j < 4; ++j)
                        acc[mt][j] = __builtin_amdgcn_mfma_f32_16x16x32_bf16(afrag, bfrag[j], acc[mt][j], 0, 0, 0);
                }
            }
        }
    }

    // epilogue: D row(m)=quad*4+reg -> cout, col(n)=n16 -> position
    const int osmp = out_s0 + smp;
#pragma unroll
    for (int j = 0; j < 4; ++j) {
        int pos = (y0 + wv) * 64 + j * 16 + n16;
#pragma unroll
        for (int mt = 0; mt < MT; ++mt) {
            int coutb = co0 + mt * 16 + quad * 4;
            float b0 = 0.f, b1 = 0.f, b2 = 0.f, b3 = 0.f;
            if constexpr (EPI != 1) {
                float4 bv = *(const float4*)&bias[coutb];
                b0 = bv.x; b1 = bv.y; b2 = bv.z; b3 = bv.w;
            }
            float v0 = acc[mt][j][0] + b0;
            float v1 = acc[mt][j][1] + b1;
            float v2 = acc[mt][j][2] + b2;
            float v3 = acc[mt][j][3] + b3;
            if constexpr (EPI == 1 || EPI == 2 || EPI == 3) {
                if constexpr (EPI == 2) {
                    const float* xr = (const float*)res + (size_t)osmp * 131072 + (size_t)coutb * 4096 + pos;
                    v0 += xr[0]; v1 += xr[4096]; v2 += xr[8192]; v3 += xr[12288];
                } else if constexpr (EPI == 3) {
                    v0 = gelu_new(v0); v1 = gelu_new(v1); v2 = gelu_new(v2); v3 = gelu_new(v3);
                }
                ushort4 st;
                st.x = f2bu(v0); st.y = f2bu(v1); st.z = f2bu(v2); st.w = f2bu(v3);
                *(ushort4*)&((bf16*)out)[((size_t)osmp * 4096 + pos) * CO_TOTAL + coutb] = st;
            } else {
                ushort4 rv = *(const ushort4*)&((const bf16*)res)[((size_t)osmp * 4096 + pos) * 32 + coutb];
                v0 += su2f(rv.x); v1 += su2f(rv.y); v2 += su2f(rv.z); v3 += su2f(rv.w);
                float* op = (float*)out + (size_t)osmp * 131072 + (size_t)coutb * 4096 + pos;
                op[0] = v0; op[4096] = v1; op[8192] = v2; op[12288] = v3;
            }
        }
    }
}

// ---------------- stride-2 conv (k,q): round-7 path, small workload ----------
template <int CI, int CI_BLK, int CO_TOTAL, int CO_BLK, int S, int EPI>
__global__ __launch_bounds__(256) void conv_mfma(const bf16* __restrict__ in,
                                                 const bf16* __restrict__ wpk,
                                                 const float* __restrict__ bias,
                                                 const void* __restrict__ res,
                                                 void* __restrict__ out,
                                                 int in_s0, int out_s0) {
    constexpr int WO = 64 / S;
    constexpr int HO = 64 / S;
    constexpr int NG = (HO * WO) / 256;
    constexpr int TPR = WO / 16;
    constexpr int MT = CO_BLK / 16;
    constexpr int PHASES = CI / CI_BLK;
    constexpr int KC = CI_BLK / 32;
    constexpr int PAD = CI_BLK + 8;

    __shared__ short s_w[9 * CO_BLK * PAD];

    const int tid = threadIdx.x;
    const int lane = tid & 63;
    const int wv = tid >> 6;
    const int quad = lane >> 4;
    const int n16 = lane & 15;

    const int ng = blockIdx.x % NG;
    const int cg = blockIdx.x / NG;
    const int co0 = cg * CO_BLK;
    const int smp = blockIdx.y;

    f32x4 acc[MT][4];
#pragma unroll
    for (int mt = 0; mt < MT; ++mt)
#pragma unroll
        for (int j = 0; j < 4; ++j) acc[mt][j] = (f32x4){0.f, 0.f, 0.f, 0.f};

    const size_t in_base = (size_t)(in_s0 + smp) * 4096 * CI;

    for (int phase = 0; phase < PHASES; ++phase) {
        const int ci0 = phase * CI_BLK;
        __syncthreads();
        for (int idx = tid; idx < 9 * CO_BLK * CI_BLK / 4; idx += 256) {
            int e = idx * 4;
            int tap = e / (CO_BLK * CI_BLK);
            int rem = e - tap * (CO_BLK * CI_BLK);
            int col = rem / CI_BLK;
            int k = rem - col * CI_BLK;
            const ushort4 src = *(const ushort4*)&wpk[((size_t)tap * CO_TOTAL + co0 + col) * CI + ci0 + k];
            *(ushort4*)&s_w[(tap * CO_BLK + col) * PAD + k] = src;
        }
        __syncthreads();

#pragma unroll
        for (int ky = 0; ky < 3; ++ky) {
#pragma unroll
            for (int kx = 0; kx < 3; ++kx) {
                const int tap = ky * 3 + kx;
                bf16x8 bfrag[KC][4];
#pragma unroll
                for (int kc = 0; kc < KC; ++kc) {
#pragma unroll
                    for (int j = 0; j < 4; ++j) {
                        int tile = ng * 16 + wv * 4 + j;
                        int yo = tile / TPR;
                        int xo = (tile % TPR) * 16;
                        int xi = (xo + n16) * S + kx - 1;
                        int yi = yo * S + ky - 1;
                        bool valid = (xi >= 0) && (xi < 64) && (yi >= 0) && (yi < 64);
                        uint4 u;
                        if (valid)
                            u = *(const uint4*)&in[in_base + ((size_t)yi * 64 + xi) * CI + ci0 + kc * 32 + quad * 8];
                        else
                            u = make_uint4(0u, 0u, 0u, 0u);
                        __builtin_memcpy(&bfrag[kc][j], &u, 16);
                    }
                }
#pragma unroll
                for (int kc = 0; kc < KC; ++kc) {
#pragma unroll
                    for (int mt = 0; mt < MT; ++mt) {
                        bf16x8 afrag = *(const bf16x8*)&s_w[(tap * CO_BLK + mt * 16 + n16) * PAD + kc * 32 + quad * 8];
#pragma unroll
                        for (int j = 0; j < 4; ++j)
                            acc[mt][j] = __builtin_amdgcn_mfma_f32_16x16x32_bf16(afrag, bfrag[kc][j], acc[mt][j], 0, 0, 0);
                    }
                }
            }
        }
    }

    const int osmp = out_s0 + smp;
#pragma unroll
    for (int j = 0; j < 4; ++j) {
        int tile = ng * 16 + wv * 4 + j;
        int yo = tile / TPR;
        int xo = (tile % TPR) * 16;
        int pos = yo * WO + xo + n16;
#pragma unroll
        for (int mt = 0; mt < MT; ++mt) {
            int coutb = co0 + mt * 16 + quad * 4;
            float v0 = acc[mt][j][0];
            float v1 = acc[mt][j][1];
            float v2 = acc[mt][j][2];
            float v3 = acc[mt][j][3];
            ushort4 st;
            st.x = f2bu(v0); st.y = f2bu(v1); st.z = f2bu(v2); st.w = f2bu(v3);
            *(ushort4*)&((bf16*)out)[((size_t)osmp * HO * WO + pos) * CO_TOTAL + coutb] = st;
        }
    }
}

// ---------------- attention: scores + softmax (bf16 output) ----------------
__global__ __launch_bounds__(256) void attn_scores_k(const bf16* __restrict__ Q,
                                                     const bf16* __restrict__ K,
                                                     bf16* __restrict__ att) {
    __shared__ float s_q[4096];
    __shared__ float rs[256];
    __shared__ float s_att[32];
    const int tid = threadIdx.x;
    const int t = blockIdx.x & 31;
    const int h = (blockIdx.x >> 5) & 7;
    const int b = blockIdx.x >> 8;

    const bf16* qrow = Q + (size_t)(b * 32 + t) * 32768 + h * 4;
    for (int i = tid; i < 4096; i += 256) {
        int p = i >> 2, cl = i & 3;
        s_q[i] = b2f(qrow[(size_t)p * 32 + cl]);
    }
    __syncthreads();

    for (int s = 0; s < 32; ++s) {
        const bf16* krow = K + (size_t)(b * 32 + s) * 32768 + h * 4;
        float p = 0.f;
        for (int d = tid; d < 4096; d += 256) {
            int pp = d >> 2, cl = d & 3;
            p += s_q[d] * b2f(krow[(size_t)pp * 32 + cl]);
        }
        rs[tid] = p;
        __syncthreads();
        for (int off = 128; off > 0; off >>= 1) {
            if (tid < off) rs[tid] += rs[tid + off];
            __syncthreads();
        }
        if (tid == 0) s_att[s] = rs[0] * (1.0f / 64.0f);
        __syncthreads();
    }
    if (tid == 0) {
        float mx = -1e30f;
        for (int i = 0; i < 32; ++i) mx = fmaxf(mx, s_att[i]);
        float sum = 0.f;
        for (int i = 0; i < 32; ++i) { s_att[i] = expf(s_att[i] - mx); sum += s_att[i]; }
        float inv = 1.f / sum;
        for (int i = 0; i < 32; ++i) att[(size_t)blockIdx.x * 32 + i] = f2b(s_att[i] * inv);
    }
}

// ---------------- y = att @ v : MFMA with fused in-LDS V transpose ----------
__global__ __launch_bounds__(256) void attn_apply_mfma(const bf16* __restrict__ att,
                                                       const bf16* __restrict__ V,
                                                       bf16* __restrict__ Y) {
    __shared__ short vlds[512 * 40];
    __shared__ short ylds[32 * 512];
    const int tid = threadIdx.x;
    const int lane = tid & 63;
    const int wv = tid >> 6;
    const int quad = lane >> 4;
    const int n16 = lane & 15;
    const int pb = blockIdx.x;
    const int b = blockIdx.y;

    for (int l = 0; l < 8; ++l) {
        int u = l * 256 + tid;
        int s = u >> 6;
        int col8 = (u & 63) * 8;
        uint4 v = *(const uint4*)&V[(((size_t)(b * 32 + s) * 4096 + pb * 16) * 32) + col8];
        unsigned short us[8];
        __builtin_memcpy(us, &v, 16);
#pragma unroll
        for (int j = 0; j < 8; ++j) {
            int idx = col8 + j;
            int p = idx >> 5, c = idx & 31;
            int row = ((c >> 2) * 16 + p) * 4 + (c & 3);
            vlds[row * 40 + s] = (short)us[j];
        }
    }
    __syncthreads();

    const int e = wv * 16 + n16;
    const int p = e >> 2, cl = e & 3;
    for (int h = 0; h < 8; ++h) {
        bf16x8 bfrag = *(const bf16x8*)&vlds[(h * 64 + e) * 40 + quad * 8];
        const int c = h * 4 + cl;
#pragma unroll
        for (int mt = 0; mt < 2; ++mt) {
            bf16x8 afrag = *(const bf16x8*)&att[((size_t)(b * 8 + h) * 32 + mt * 16 + n16) * 32 + quad * 8];
            f32x4 d = __builtin_amdgcn_mfma_f32_16x16x32_bf16(afrag, bfrag,
                                                              (f32x4){0.f, 0.f, 0.f, 0.f}, 0, 0, 0);
#pragma unroll
            for (int r = 0; r < 4; ++r) {
                int t = mt * 16 + quad * 4 + r;
                ylds[t * 512 + p * 32 + c] = (short)f2bu(d[r]);
            }
        }
    }
    __syncthreads();

    for (int l = 0; l < 8; ++l) {
        int u = l * 256 + tid;
        int t = u >> 6;
        int col8 = (u & 63) * 8;
        *(uint4*)&Y[(((size_t)(b * 32 + t) * 4096 + pb * 16) * 32) + col8] =
            *(const uint4*)&ylds[t * 512 + col8];
    }
}

extern "C" void kernel_launch(void* const* d_in, const int* in_sizes, int n_in,
                              void* d_out, int out_size, void* d_ws, size_t ws_size,
                              hipStream_t stream) {
    const float* x   = (const float*)d_in[0];
    const float* n1g = (const float*)d_in[1];
    const float* n1b = (const float*)d_in[2];
    const float* n2g = (const float*)d_in[3];
    const float* n2b = (const float*)d_in[4];
    const float* Wk  = (const float*)d_in[5];
    const float* Wq  = (const float*)d_in[6];
    const float* Wv  = (const float*)d_in[7];
    const float* Wo  = (const float*)d_in[8];
    const float* bo  = (const float*)d_in[9];
    const float* Wm1 = (const float*)d_in[10];
    const float* bm1 = (const float*)d_in[11];
    const float* Wm2 = (const float*)d_in[12];
    const float* bm2 = (const float*)d_in[13];

    char* ws = (char*)d_ws;
    const size_t A_OFF = 0;
    const size_t B_OFF = 33554432;
    const size_t D_OFF = 67108864;
    const size_t E_OFF = 67239936;
    const size_t F_OFF = 67461120;
    const size_t C_OFF = 68519936;
    const size_t Q_OFF = C_OFF + 8388608;

    bf16*  xn   = (bf16*)(ws + A_OFF);
    bf16*  Yb   = (bf16*)(ws + A_OFF);
    bf16*  xn2  = (bf16*)(ws + A_OFF);
    bf16*  Vb   = (bf16*)(ws + B_OFF);
    bf16*  X1   = (bf16*)(ws + B_OFF);
    bf16*  attbf = (bf16*)(ws + D_OFF);
    bf16*  wpk_k  = (bf16*)(ws + E_OFF);
    bf16*  wpk_q  = (bf16*)(ws + E_OFF + 18432);
    bf16*  wpk_v  = (bf16*)(ws + E_OFF + 36864);
    bf16*  wpk_o  = (bf16*)(ws + E_OFF + 55296);
    bf16*  wpk_m1 = (bf16*)(ws + E_OFF + 73728);
    bf16*  wpk_m2 = (bf16*)(ws + E_OFF + 147456);
    float* g2t  = (float*)(ws + F_OFF);
    float* b2t  = (float*)(ws + F_OFF + 524288);
    float2* spart = (float2*)(ws + F_OFF + 1048576);
    float2* stats = (float2*)(ws + F_OFF + 1056768);
    bf16*  Kb   = (bf16*)(ws + C_OFF);
    bf16*  Qb   = (bf16*)(ws + Q_OFF);
    bf16*  Hb   = (bf16*)(ws + C_OFF);

    const size_t HB_PER_SAMPLE = 1048576;
    int chunk = 128;
    if (ws_size < C_OFF + 128 * HB_PER_SAMPLE) {
        size_t avail = (ws_size > C_OFF) ? (ws_size - C_OFF) : HB_PER_SAMPLE;
        chunk = (int)(avail / HB_PER_SAMPLE);
        if (chunk < 1) chunk = 1;
        if (chunk > 128) chunk = 128;
    }

    // 0. pack weights; transpose LN2 gamma/beta
    pack_w<<<36, 256, 0, stream>>>(Wk, wpk_k, 32, 32);
    pack_w<<<36, 256, 0, stream>>>(Wq, wpk_q, 32, 32);
    pack_w<<<36, 256, 0, stream>>>(Wv, wpk_v, 32, 32);
    pack_w<<<36, 256, 0, stream>>>(Wo, wpk_o, 32, 32);
    pack_w<<<144, 256, 0, stream>>>(Wm1, wpk_m1, 128, 32);
    pack_w<<<144, 256, 0, stream>>>(Wm2, wpk_m2, 32, 128);
    gtrans_k<<<1024, 256, 0, stream>>>(n2g, n2b, g2t, b2t);

    // 1. LN1: x (NCHW f32) -> xn (NHWC bf16)
    ln_part<float><<<dim3(8, 128), 256, 0, stream>>>(x, spart);
    ln_fin<<<1, 128, 0, stream>>>(spart, stats);
    ln1_norm_t<<<dim3(32, 128), 256, 0, stream>>>(x, n1g, n1b, stats, xn);
    // 2-4. k,q (stride 2, old path), v (stride 1, LDS path)
    conv_mfma<32, 32, 32, 32, 2, 1><<<dim3(4, 128), 256, 0, stream>>>(xn, wpk_k, nullptr, nullptr, Kb, 0, 0);
    conv_mfma<32, 32, 32, 32, 2, 1><<<dim3(4, 128), 256, 0, stream>>>(xn, wpk_q, nullptr, nullptr, Qb, 0, 0);
    conv_lds<32, 32, 32, 1><<<dim3(16, 128), 256, 0, stream>>>(xn, wpk_v, nullptr, nullptr, Vb, 0, 0);
    // 5. attention scores + softmax -> bf16 att
    attn_scores_k<<<1024, 256, 0, stream>>>(Qb, Kb, attbf);
    // 6. y = att @ v
    attn_apply_mfma<<<dim3(256, 4), 256, 0, stream>>>(attbf, Vb, Yb);
    // 7. Wo conv + bias + residual x -> X1
    conv_lds<32, 32, 32, 2><<<dim3(16, 128), 256, 0, stream>>>(Yb, wpk_o, bo, x, X1, 0, 0);
    // 8. LN2
    ln_part<bf16><<<dim3(8, 128), 256, 0, stream>>>(X1, spart);
    ln_fin<<<1, 128, 0, stream>>>(spart, stats);
    ln2_norm<<<dim3(64, 128), 256, 0, stream>>>(X1, g2t, b2t, stats, xn2);
    // 9-10. mixer (CO_BLK=64 for Wm1 -> CGRP=2; Wm2 CHUNKS=4)
    for (int s0 = 0; s0 < 128; s0 += chunk) {
        int n = (128 - s0 < chunk) ? (128 - s0) : chunk;
        conv_lds<32, 128, 64, 3><<<dim3(32, n), 256, 0, stream>>>(xn2, wpk_m1, bm1, nullptr, Hb, s0, 0);
        conv_lds<128, 32, 32, 4><<<dim3(16, n), 256, 0, stream>>>(Hb, wpk_m2, bm2, X1, (float*)d_out, 0, s0);
    }
}

// Round 9
// 567.255 us; speedup vs baseline: 7.0268x; 1.1972x over previous
//
#include <hip/hip_runtime.h>
#include <hip/hip_bf16.h>

using bf16 = __hip_bfloat16;
typedef short bf16x8 __attribute__((ext_vector_type(8)));
typedef float f32x4 __attribute__((ext_vector_type(4)));

__device__ inline float b2f(bf16 h) { return __bfloat162float(h); }
__device__ inline bf16 f2b(float f) { return __float2bfloat16(f); }
__device__ inline unsigned short f2bu(float f) {
    bf16 h = __float2bfloat16(f);
    unsigned short u;
    __builtin_memcpy(&u, &h, 2);
    return u;
}
__device__ inline float su2f(unsigned short u) {
    unsigned v = ((unsigned)u) << 16;
    return __uint_as_float(v);
}
__device__ inline float gelu_new(float x) {
    float x3 = x * x * x;
    return 0.5f * x * (1.0f + tanhf(0.7978845608028654f * (x + 0.044715f * x3)));
}

// ---------------- weight pack: [O][I][3][3] f32 -> [tap][O][I] bf16 ----------
__global__ __launch_bounds__(256) void pack_w(const float* __restrict__ w,
                                              bf16* __restrict__ wpk,
                                              int CO, int CI) {
    int i = blockIdx.x * 256 + threadIdx.x;
    int total = CO * CI * 9;
    if (i < total) {
        int tap = i % 9;
        int ci = (i / 9) % CI;
        int co = i / (9 * CI);
        wpk[((size_t)tap * CO + co) * CI + ci] = f2b(w[i]);
    }
}

// ---------------- g/b transpose NCHW f32 -> NHWC f32 ----------
__global__ __launch_bounds__(256) void gtrans_k(const float* __restrict__ g,
                                                const float* __restrict__ bb,
                                                float* __restrict__ gt,
                                                float* __restrict__ bt) {
    int i = blockIdx.x * 256 + threadIdx.x;
    int sel = i >> 17;
    int o = i & 131071;
    int p = o >> 5, c = o & 31;
    int src = c * 4096 + p;
    if (sel == 0) gt[o] = g[src];
    else          bt[o] = bb[src];
}

// ---------------- LN partial reduce: grid (8, 128) ----------------
template <typename TIN>
__global__ __launch_bounds__(256) void ln_part(const void* __restrict__ xin,
                                               float2* __restrict__ spart) {
    const int tid = threadIdx.x;
    const int sample = blockIdx.y, seg = blockIdx.x;
    const size_t base = (size_t)sample * 131072 + seg * 16384;
    float sum = 0.f, ss = 0.f;
    if constexpr (sizeof(TIN) == 4) {
        const float4* p = (const float4*)((const float*)xin + base);
        for (int l = 0; l < 16; ++l) {
            float4 v = p[l * 256 + tid];
            sum += v.x + v.y + v.z + v.w;
            ss += v.x * v.x + v.y * v.y + v.z * v.z + v.w * v.w;
        }
    } else {
        const uint4* p = (const uint4*)((const bf16*)xin + base);
        for (int l = 0; l < 8; ++l) {
            uint4 u = p[l * 256 + tid];
            unsigned w[4] = {u.x, u.y, u.z, u.w};
#pragma unroll
            for (int j = 0; j < 4; ++j) {
                float lo = __uint_as_float(w[j] << 16);
                float hi = __uint_as_float(w[j] & 0xffff0000u);
                sum += lo + hi;
                ss += lo * lo + hi * hi;
            }
        }
    }
    __shared__ float rs[256], rs2[256];
    rs[tid] = sum; rs2[tid] = ss;
    __syncthreads();
    for (int off = 128; off > 0; off >>= 1) {
        if (tid < off) { rs[tid] += rs[tid + off]; rs2[tid] += rs2[tid + off]; }
        __syncthreads();
    }
    if (tid == 0) spart[sample * 8 + seg] = make_float2(rs[0], rs2[0]);
}

// ---------------- LN finalize ----------------
__global__ __launch_bounds__(128) void ln_fin(const float2* __restrict__ spart,
                                              float2* __restrict__ stats) {
    int t = threadIdx.x;
    float s = 0.f, ss = 0.f;
    for (int j = 0; j < 8; ++j) {
        float2 v = spart[t * 8 + j];
        s += v.x; ss += v.y;
    }
    float m = s / 131072.f;
    float var = ss / 131072.f - m * m;
    stats[t] = make_float2(m, rsqrtf(var + 1e-5f));
}

// ---------------- LN1 normalize + NCHW->NHWC transpose ----------------
__global__ __launch_bounds__(256) void ln1_norm_t(const float* __restrict__ x,
                                                  const float* __restrict__ g,
                                                  const float* __restrict__ bb,
                                                  const float2* __restrict__ stats,
                                                  bf16* __restrict__ out) {
    __shared__ float tile[32][129];
    const int tid = threadIdx.x;
    const int sample = blockIdx.y;
    const int p0 = blockIdx.x * 128;
    float2 st = stats[sample];
    const float m = st.x, r = st.y;
    const size_t xb = (size_t)sample * 131072;
    for (int k = 0; k < 16; ++k) {
        int idx = k * 256 + tid;
        int c = idx >> 7, p = idx & 127;
        int gi = c * 4096 + p0 + p;
        float v = x[xb + gi];
        tile[c][p] = (v - m) * r * g[gi] + bb[gi];
    }
    __syncthreads();
    for (int k = 0; k < 8; ++k) {
        int idx = k * 256 + tid;
        int p = idx >> 4, c2 = (idx & 15) * 2;
        unsigned lo = (unsigned)f2bu(tile[c2][p]);
        unsigned hi = (unsigned)f2bu(tile[c2 + 1][p]);
        *(unsigned*)&out[xb + (size_t)(p0 + p) * 32 + c2] = lo | (hi << 16);
    }
}

// ---------------- LN2 normalize, NHWC linear ----------------
__global__ __launch_bounds__(256) void ln2_norm(const bf16* __restrict__ xin,
                                                const float* __restrict__ gt,
                                                const float* __restrict__ bt,
                                                const float2* __restrict__ stats,
                                                bf16* __restrict__ out) {
    const int tid = threadIdx.x;
    const int sample = blockIdx.y;
    float2 st = stats[sample];
    const float m = st.x, r = st.y;
    int i0 = (blockIdx.x * 256 + tid) * 8;
    const size_t base = (size_t)sample * 131072 + i0;
    uint4 u = *(const uint4*)&xin[base];
    float4 g0 = *(const float4*)&gt[i0];
    float4 g1 = *(const float4*)&gt[i0 + 4];
    float4 b0 = *(const float4*)&bt[i0];
    float4 b1 = *(const float4*)&bt[i0 + 4];
    unsigned w[4] = {u.x, u.y, u.z, u.w};
    float gv[8] = {g0.x, g0.y, g0.z, g0.w, g1.x, g1.y, g1.z, g1.w};
    float bv[8] = {b0.x, b0.y, b0.z, b0.w, b1.x, b1.y, b1.z, b1.w};
    unsigned o[4];
#pragma unroll
    for (int j = 0; j < 4; ++j) {
        float lo = __uint_as_float(w[j] << 16);
        float hi = __uint_as_float(w[j] & 0xffff0000u);
        lo = (lo - m) * r * gv[2 * j] + bv[2 * j];
        hi = (hi - m) * r * gv[2 * j + 1] + bv[2 * j + 1];
        o[j] = (unsigned)f2bu(lo) | ((unsigned)f2bu(hi) << 16);
    }
    uint4 st4 = make_uint4(o[0], o[1], o[2], o[3]);
    *(uint4*)&out[base] = st4;
}

// ---------------- stride-1 conv: both operands staged in LDS ----------------
template <int CI, int CO_TOTAL, int CO_BLK, int EPI>
__global__ __launch_bounds__(256) void conv_lds(const bf16* __restrict__ in,
                                                const bf16* __restrict__ wpk,
                                                const float* __restrict__ bias,
                                                const void* __restrict__ res,
                                                void* __restrict__ out,
                                                int in_s0, int out_s0) {
    constexpr int CHUNKS = CI / 32;
    constexpr int MT = CO_BLK / 16;
    constexpr int NG = 16;

    __shared__ short s_in[6 * 66 * 32];
    __shared__ short s_w[9 * CO_BLK * 32];

    const int tid = threadIdx.x;
    const int lane = tid & 63;
    const int wv = tid >> 6;
    const int quad = lane >> 4;
    const int n16 = lane & 15;

    const int ng = blockIdx.x % NG;
    const int cg = blockIdx.x / NG;
    const int co0 = cg * CO_BLK;
    const int smp = blockIdx.y;
    const int y0 = ng * 4;

    f32x4 acc[MT][4];
#pragma unroll
    for (int mt = 0; mt < MT; ++mt)
#pragma unroll
        for (int j = 0; j < 4; ++j) acc[mt][j] = (f32x4){0.f, 0.f, 0.f, 0.f};

    const size_t in_base = (size_t)(in_s0 + smp) * 4096 * CI;

    for (int chunk = 0; chunk < CHUNKS; ++chunk) {
        const int ci0 = chunk * 32;
        __syncthreads();
        for (int i = tid; i < 6 * 66 * 4; i += 256) {
            int sub = i & 3;
            int x = (i >> 2) % 66;
            int row = i / 264;
            int y = y0 + row - 1;
            int xg = x - 1;
            uint4 u = make_uint4(0u, 0u, 0u, 0u);
            if (y >= 0 && y < 64 && xg >= 0 && xg < 64)
                u = *(const uint4*)&in[in_base + ((size_t)y * 64 + xg) * CI + ci0 + sub * 8];
            int ps = sub ^ (x & 3) ^ ((x >> 2) & 1);
            *(uint4*)&s_in[(row * 66 + x) * 32 + ps * 8] = u;
        }
        for (int i = tid; i < 9 * CO_BLK * 4; i += 256) {
            int sub = i & 3;
            int co = (i >> 2) % CO_BLK;
            int tap = i / (CO_BLK * 4);
            uint4 u = *(const uint4*)&wpk[((size_t)tap * CO_TOTAL + co0 + co) * CI + ci0 + sub * 8];
            int ps = sub ^ (co & 3) ^ ((co >> 2) & 1);
            *(uint4*)&s_w[(tap * CO_BLK + co) * 32 + ps * 8] = u;
        }
        __syncthreads();

#pragma unroll
        for (int ky = 0; ky < 3; ++ky) {
#pragma unroll
            for (int kx = 0; kx < 3; ++kx) {
                const int tap = ky * 3 + kx;
                bf16x8 bfrag[4];
#pragma unroll
                for (int j = 0; j < 4; ++j) {
                    int x = j * 16 + n16 + kx;
                    int ps = quad ^ (x & 3) ^ ((x >> 2) & 1);
                    bfrag[j] = *(const bf16x8*)&s_in[((wv + ky) * 66 + x) * 32 + ps * 8];
                }
#pragma unroll
                for (int mt = 0; mt < MT; ++mt) {
                    int mrow = mt * 16 + n16;
                    int ps = quad ^ (mrow & 3) ^ ((mrow >> 2) & 1);
                    bf16x8 afrag = *(const bf16x8*)&s_w[(tap * CO_BLK + mrow) * 32 + ps * 8];
#pragma unroll
                    for (int j = 0; j < 4; ++j)
                        acc[mt][j] = __builtin_amdgcn_mfma_f32_16x16x32_bf16(afrag, bfrag[j], acc[mt][j], 0, 0, 0);
                }
            }
        }
    }

    const int osmp = out_s0 + smp;
#pragma unroll
    for (int j = 0; j < 4; ++j) {
        int pos = (y0 + wv) * 64 + j * 16 + n16;
#pragma unroll
        for (int mt = 0; mt < MT; ++mt) {
            int coutb = co0 + mt * 16 + quad * 4;
            float b0 = 0.f, b1 = 0.f, b2 = 0.f, b3 = 0.f;
            if constexpr (EPI != 1) {
                float4 bv = *(const float4*)&bias[coutb];
                b0 = bv.x; b1 = bv.y; b2 = bv.z; b3 = bv.w;
            }
            float v0 = acc[mt][j][0] + b0;
            float v1 = acc[mt][j][1] + b1;
            float v2 = acc[mt][j][2] + b2;
            float v3 = acc[mt][j][3] + b3;
            if constexpr (EPI == 1 || EPI == 2 || EPI == 3) {
                if constexpr (EPI == 2) {
                    const float* xr = (const float*)res + (size_t)osmp * 131072 + (size_t)coutb * 4096 + pos;
                    v0 += xr[0]; v1 += xr[4096]; v2 += xr[8192]; v3 += xr[12288];
                } else if constexpr (EPI == 3) {
                    v0 = gelu_new(v0); v1 = gelu_new(v1); v2 = gelu_new(v2); v3 = gelu_new(v3);
                }
                ushort4 st;
                st.x = f2bu(v0); st.y = f2bu(v1); st.z = f2bu(v2); st.w = f2bu(v3);
                *(ushort4*)&((bf16*)out)[((size_t)osmp * 4096 + pos) * CO_TOTAL + coutb] = st;
            } else {
                ushort4 rv = *(const ushort4*)&((const bf16*)res)[((size_t)osmp * 4096 + pos) * 32 + coutb];
                v0 += su2f(rv.x); v1 += su2f(rv.y); v2 += su2f(rv.z); v3 += su2f(rv.w);
                float* op = (float*)out + (size_t)osmp * 131072 + (size_t)coutb * 4096 + pos;
                op[0] = v0; op[4096] = v1; op[8192] = v2; op[12288] = v3;
            }
        }
    }
}

// ---------------- stride-2 conv (k,q) ----------------
template <int CI, int CI_BLK, int CO_TOTAL, int CO_BLK, int S, int EPI>
__global__ __launch_bounds__(256) void conv_mfma(const bf16* __restrict__ in,
                                                 const bf16* __restrict__ wpk,
                                                 const float* __restrict__ bias,
                                                 const void* __restrict__ res,
                                                 void* __restrict__ out,
                                                 int in_s0, int out_s0) {
    constexpr int WO = 64 / S;
    constexpr int HO = 64 / S;
    constexpr int NG = (HO * WO) / 256;
    constexpr int TPR = WO / 16;
    constexpr int MT = CO_BLK / 16;
    constexpr int PHASES = CI / CI_BLK;
    constexpr int KC = CI_BLK / 32;
    constexpr int PAD = CI_BLK + 8;

    __shared__ short s_w[9 * CO_BLK * PAD];

    const int tid = threadIdx.x;
    const int lane = tid & 63;
    const int wv = tid >> 6;
    const int quad = lane >> 4;
    const int n16 = lane & 15;

    const int ng = blockIdx.x % NG;
    const int cg = blockIdx.x / NG;
    const int co0 = cg * CO_BLK;
    const int smp = blockIdx.y;

    f32x4 acc[MT][4];
#pragma unroll
    for (int mt = 0; mt < MT; ++mt)
#pragma unroll
        for (int j = 0; j < 4; ++j) acc[mt][j] = (f32x4){0.f, 0.f, 0.f, 0.f};

    const size_t in_base = (size_t)(in_s0 + smp) * 4096 * CI;

    for (int phase = 0; phase < PHASES; ++phase) {
        const int ci0 = phase * CI_BLK;
        __syncthreads();
        for (int idx = tid; idx < 9 * CO_BLK * CI_BLK / 4; idx += 256) {
            int e = idx * 4;
            int tap = e / (CO_BLK * CI_BLK);
            int rem = e - tap * (CO_BLK * CI_BLK);
            int col = rem / CI_BLK;
            int k = rem - col * CI_BLK;
            const ushort4 src = *(const ushort4*)&wpk[((size_t)tap * CO_TOTAL + co0 + col) * CI + ci0 + k];
            *(ushort4*)&s_w[(tap * CO_BLK + col) * PAD + k] = src;
        }
        __syncthreads();

#pragma unroll
        for (int ky = 0; ky < 3; ++ky) {
#pragma unroll
            for (int kx = 0; kx < 3; ++kx) {
                const int tap = ky * 3 + kx;
                bf16x8 bfrag[KC][4];
#pragma unroll
                for (int kc = 0; kc < KC; ++kc) {
#pragma unroll
                    for (int j = 0; j < 4; ++j) {
                        int tile = ng * 16 + wv * 4 + j;
                        int yo = tile / TPR;
                        int xo = (tile % TPR) * 16;
                        int xi = (xo + n16) * S + kx - 1;
                        int yi = yo * S + ky - 1;
                        bool valid = (xi >= 0) && (xi < 64) && (yi >= 0) && (yi < 64);
                        uint4 u;
                        if (valid)
                            u = *(const uint4*)&in[in_base + ((size_t)yi * 64 + xi) * CI + ci0 + kc * 32 + quad * 8];
                        else
                            u = make_uint4(0u, 0u, 0u, 0u);
                        __builtin_memcpy(&bfrag[kc][j], &u, 16);
                    }
                }
#pragma unroll
                for (int kc = 0; kc < KC; ++kc) {
#pragma unroll
                    for (int mt = 0; mt < MT; ++mt) {
                        bf16x8 afrag = *(const bf16x8*)&s_w[(tap * CO_BLK + mt * 16 + n16) * PAD + kc * 32 + quad * 8];
#pragma unroll
                        for (int j = 0; j < 4; ++j)
                            acc[mt][j] = __builtin_amdgcn_mfma_f32_16x16x32_bf16(afrag, bfrag[kc][j], acc[mt][j], 0, 0, 0);
                    }
                }
            }
        }
    }

    const int osmp = out_s0 + smp;
#pragma unroll
    for (int j = 0; j < 4; ++j) {
        int tile = ng * 16 + wv * 4 + j;
        int yo = tile / TPR;
        int xo = (tile % TPR) * 16;
        int pos = yo * WO + xo + n16;
#pragma unroll
        for (int mt = 0; mt < MT; ++mt) {
            int coutb = co0 + mt * 16 + quad * 4;
            ushort4 st;
            st.x = f2bu(acc[mt][j][0]); st.y = f2bu(acc[mt][j][1]);
            st.z = f2bu(acc[mt][j][2]); st.w = f2bu(acc[mt][j][3]);
            *(ushort4*)&((bf16*)out)[((size_t)osmp * HO * WO + pos) * CO_TOTAL + coutb] = st;
        }
    }
}

// ---------------- attention scores + softmax : fused MFMA ----------------
// grid 32 = (b*8+h); block 256 (4 waves). Q,K NHWC [bt][1024 p][32 c];
// head h = channels [4h,4h+4). att bf16 [b][h][t][s].
// Per wave: K-slice p in [wv*256, wv*256+256) as 32 chunks of 16x16x32 MFMA,
// 2 m-tiles (t) x 2 n-tiles (s). Cross-wave reduce in LDS, then row softmax.
__global__ __launch_bounds__(256) void attn_scores_mfma(const bf16* __restrict__ Q,
                                                        const bf16* __restrict__ K,
                                                        bf16* __restrict__ att) {
    __shared__ float red[4][32][33];
    __shared__ float sc[32][33];
    const int tid = threadIdx.x;
    const int lane = tid & 63;
    const int wv = tid >> 6;
    const int quad = lane >> 4;
    const int n16 = lane & 15;
    const int h = blockIdx.x & 7;
    const int b = blockIdx.x >> 3;
    const size_t base = (size_t)b * 32 * 32768 + (size_t)h * 4;

    f32x4 acc[2][2];
#pragma unroll
    for (int mt = 0; mt < 2; ++mt)
#pragma unroll
        for (int nt = 0; nt < 2; ++nt) acc[mt][nt] = (f32x4){0.f, 0.f, 0.f, 0.f};

    for (int kc = 0; kc < 32; ++kc) {
        const int p0 = wv * 256 + kc * 8 + quad * 2;
        bf16x8 afrag[2], bfrag[2];
#pragma unroll
        for (int mt = 0; mt < 2; ++mt) {
            const bf16* qp = &Q[base + (size_t)(mt * 16 + n16) * 32768 + (size_t)p0 * 32];
            uint2 lo = *(const uint2*)qp;
            uint2 hi = *(const uint2*)(qp + 32);
            uint4 u = make_uint4(lo.x, lo.y, hi.x, hi.y);
            __builtin_memcpy(&afrag[mt], &u, 16);
        }
#pragma unroll
        for (int nt = 0; nt < 2; ++nt) {
            const bf16* kp = &K[base + (size_t)(nt * 16 + n16) * 32768 + (size_t)p0 * 32];
            uint2 lo = *(const uint2*)kp;
            uint2 hi = *(const uint2*)(kp + 32);
            uint4 u = make_uint4(lo.x, lo.y, hi.x, hi.y);
            __builtin_memcpy(&bfrag[nt], &u, 16);
        }
#pragma unroll
        for (int mt = 0; mt < 2; ++mt)
#pragma unroll
            for (int nt = 0; nt < 2; ++nt)
                acc[mt][nt] = __builtin_amdgcn_mfma_f32_16x16x32_bf16(afrag[mt], bfrag[nt], acc[mt][nt], 0, 0, 0);
    }
#pragma unroll
    for (int mt = 0; mt < 2; ++mt)
#pragma unroll
        for (int nt = 0; nt < 2; ++nt)
#pragma unroll
            for (int r = 0; r < 4; ++r)
                red[wv][mt * 16 + quad * 4 + r][nt * 16 + n16] = acc[mt][nt][r];
    __syncthreads();
    for (int i = tid; i < 1024; i += 256) {
        int t = i >> 5, s = i & 31;
        sc[t][s] = (red[0][t][s] + red[1][t][s] + red[2][t][s] + red[3][t][s]) * (1.0f / 64.0f);
    }
    __syncthreads();
    if (tid < 32) {
        float mx = -1e30f;
        for (int s2 = 0; s2 < 32; ++s2) mx = fmaxf(mx, sc[tid][s2]);
        float sum = 0.f;
        for (int s2 = 0; s2 < 32; ++s2) sum += expf(sc[tid][s2] - mx);
        float inv = 1.f / sum;
        bf16* arow = &att[((size_t)blockIdx.x * 32 + tid) * 32];
        for (int s2 = 0; s2 < 32; ++s2) arow[s2] = f2b(expf(sc[tid][s2] - mx) * inv);
    }
}

// ---------------- y = att @ v : MFMA with fused in-LDS V transpose ----------
__global__ __launch_bounds__(256) void attn_apply_mfma(const bf16* __restrict__ att,
                                                       const bf16* __restrict__ V,
                                                       bf16* __restrict__ Y) {
    __shared__ short vlds[512 * 40];
    __shared__ short ylds[32 * 512];
    const int tid = threadIdx.x;
    const int lane = tid & 63;
    const int wv = tid >> 6;
    const int quad = lane >> 4;
    const int n16 = lane & 15;
    const int pb = blockIdx.x;
    const int b = blockIdx.y;

    for (int l = 0; l < 8; ++l) {
        int u = l * 256 + tid;
        int s = u >> 6;
        int col8 = (u & 63) * 8;
        uint4 v = *(const uint4*)&V[(((size_t)(b * 32 + s) * 4096 + pb * 16) * 32) + col8];
        unsigned short us[8];
        __builtin_memcpy(us, &v, 16);
#pragma unroll
        for (int j = 0; j < 8; ++j) {
            int idx = col8 + j;
            int p = idx >> 5, c = idx & 31;
            int row = ((c >> 2) * 16 + p) * 4 + (c & 3);
            vlds[row * 40 + s] = (short)us[j];
        }
    }
    __syncthreads();

    const int e = wv * 16 + n16;
    const int p = e >> 2, cl = e & 3;
    for (int h = 0; h < 8; ++h) {
        bf16x8 bfrag = *(const bf16x8*)&vlds[(h * 64 + e) * 40 + quad * 8];
        const int c = h * 4 + cl;
#pragma unroll
        for (int mt = 0; mt < 2; ++mt) {
            bf16x8 afrag = *(const bf16x8*)&att[((size_t)(b * 8 + h) * 32 + mt * 16 + n16) * 32 + quad * 8];
            f32x4 d = __builtin_amdgcn_mfma_f32_16x16x32_bf16(afrag, bfrag,
                                                              (f32x4){0.f, 0.f, 0.f, 0.f}, 0, 0, 0);
#pragma unroll
            for (int r = 0; r < 4; ++r) {
                int t = mt * 16 + quad * 4 + r;
                ylds[t * 512 + p * 32 + c] = (short)f2bu(d[r]);
            }
        }
    }
    __syncthreads();

    for (int l = 0; l < 8; ++l) {
        int u = l * 256 + tid;
        int t = u >> 6;
        int col8 = (u & 63) * 8;
        *(uint4*)&Y[(((size_t)(b * 32 + t) * 4096 + pb * 16) * 32) + col8] =
            *(const uint4*)&ylds[t * 512 + col8];
    }
}

extern "C" void kernel_launch(void* const* d_in, const int* in_sizes, int n_in,
                              void* d_out, int out_size, void* d_ws, size_t ws_size,
                              hipStream_t stream) {
    const float* x   = (const float*)d_in[0];
    const float* n1g = (const float*)d_in[1];
    const float* n1b = (const float*)d_in[2];
    const float* n2g = (const float*)d_in[3];
    const float* n2b = (const float*)d_in[4];
    const float* Wk  = (const float*)d_in[5];
    const float* Wq  = (const float*)d_in[6];
    const float* Wv  = (const float*)d_in[7];
    const float* Wo  = (const float*)d_in[8];
    const float* bo  = (const float*)d_in[9];
    const float* Wm1 = (const float*)d_in[10];
    const float* bm1 = (const float*)d_in[11];
    const float* Wm2 = (const float*)d_in[12];
    const float* bm2 = (const float*)d_in[13];

    char* ws = (char*)d_ws;
    const size_t A_OFF = 0;
    const size_t B_OFF = 33554432;
    const size_t D_OFF = 67108864;
    const size_t E_OFF = 67239936;
    const size_t F_OFF = 67461120;
    const size_t C_OFF = 68519936;
    const size_t Q_OFF = C_OFF + 8388608;

    bf16*  xn   = (bf16*)(ws + A_OFF);
    bf16*  Yb   = (bf16*)(ws + A_OFF);
    bf16*  xn2  = (bf16*)(ws + A_OFF);
    bf16*  Vb   = (bf16*)(ws + B_OFF);
    bf16*  X1   = (bf16*)(ws + B_OFF);
    bf16*  attbf = (bf16*)(ws + D_OFF);
    bf16*  wpk_k  = (bf16*)(ws + E_OFF);
    bf16*  wpk_q  = (bf16*)(ws + E_OFF + 18432);
    bf16*  wpk_v  = (bf16*)(ws + E_OFF + 36864);
    bf16*  wpk_o  = (bf16*)(ws + E_OFF + 55296);
    bf16*  wpk_m1 = (bf16*)(ws + E_OFF + 73728);
    bf16*  wpk_m2 = (bf16*)(ws + E_OFF + 147456);
    float* g2t  = (float*)(ws + F_OFF);
    float* b2t  = (float*)(ws + F_OFF + 524288);
    float2* spart = (float2*)(ws + F_OFF + 1048576);
    float2* stats = (float2*)(ws + F_OFF + 1056768);
    bf16*  Kb   = (bf16*)(ws + C_OFF);
    bf16*  Qb   = (bf16*)(ws + Q_OFF);
    bf16*  Hb   = (bf16*)(ws + C_OFF);

    const size_t HB_PER_SAMPLE = 1048576;
    int chunk = 128;
    if (ws_size < C_OFF + 128 * HB_PER_SAMPLE) {
        size_t avail = (ws_size > C_OFF) ? (ws_size - C_OFF) : HB_PER_SAMPLE;
        chunk = (int)(avail / HB_PER_SAMPLE);
        if (chunk < 1) chunk = 1;
        if (chunk > 128) chunk = 128;
    }

    // 0. pack weights; transpose LN2 gamma/beta
    pack_w<<<36, 256, 0, stream>>>(Wk, wpk_k, 32, 32);
    pack_w<<<36, 256, 0, stream>>>(Wq, wpk_q, 32, 32);
    pack_w<<<36, 256, 0, stream>>>(Wv, wpk_v, 32, 32);
    pack_w<<<36, 256, 0, stream>>>(Wo, wpk_o, 32, 32);
    pack_w<<<144, 256, 0, stream>>>(Wm1, wpk_m1, 128, 32);
    pack_w<<<144, 256, 0, stream>>>(Wm2, wpk_m2, 32, 128);
    gtrans_k<<<1024, 256, 0, stream>>>(n2g, n2b, g2t, b2t);

    // 1. LN1: x (NCHW f32) -> xn (NHWC bf16)
    ln_part<float><<<dim3(8, 128), 256, 0, stream>>>(x, spart);
    ln_fin<<<1, 128, 0, stream>>>(spart, stats);
    ln1_norm_t<<<dim3(32, 128), 256, 0, stream>>>(x, n1g, n1b, stats, xn);
    // 2-4. k,q (stride 2), v (stride 1 LDS)
    conv_mfma<32, 32, 32, 32, 2, 1><<<dim3(4, 128), 256, 0, stream>>>(xn, wpk_k, nullptr, nullptr, Kb, 0, 0);
    conv_mfma<32, 32, 32, 32, 2, 1><<<dim3(4, 128), 256, 0, stream>>>(xn, wpk_q, nullptr, nullptr, Qb, 0, 0);
    conv_lds<32, 32, 32, 1><<<dim3(16, 128), 256, 0, stream>>>(xn, wpk_v, nullptr, nullptr, Vb, 0, 0);
    // 5. attention scores + softmax (fused MFMA)
    attn_scores_mfma<<<32, 256, 0, stream>>>(Qb, Kb, attbf);
    // 6. y = att @ v
    attn_apply_mfma<<<dim3(256, 4), 256, 0, stream>>>(attbf, Vb, Yb);
    // 7. Wo conv + bias + residual x -> X1
    conv_lds<32, 32, 32, 2><<<dim3(16, 128), 256, 0, stream>>>(Yb, wpk_o, bo, x, X1, 0, 0);
    // 8. LN2
    ln_part<bf16><<<dim3(8, 128), 256, 0, stream>>>(X1, spart);
    ln_fin<<<1, 128, 0, stream>>>(spart, stats);
    ln2_norm<<<dim3(64, 128), 256, 0, stream>>>(X1, g2t, b2t, stats, xn2);
    // 9-10. mixer
    for (int s0 = 0; s0 < 128; s0 += chunk) {
        int n = (128 - s0 < chunk) ? (128 - s0) : chunk;
        conv_lds<32, 128, 64, 3><<<dim3(32, n), 256, 0, stream>>>(xn2, wpk_m1, bm1, nullptr, Hb, s0, 0);
        conv_lds<128, 32, 32, 4><<<dim3(16, n), 256, 0, stream>>>(Hb, wpk_m2, bm2, X1, (float*)d_out, 0, s0);
    }
}